// Round 2
// baseline (7027.280 us; speedup 1.0000x reference)
//
#include <hip/hip_runtime.h>
#include <hip/hip_bf16.h>

#define B_  2
#define S_  2048
#define D_  2048
#define H_  16
#define DH_ 128

// ---- typed helpers --------------------------------------------------------
__device__ inline void load8(const float* p, float* d) {
    float4 a = *(const float4*)p;
    float4 b = *(const float4*)(p + 4);
    d[0] = a.x; d[1] = a.y; d[2] = a.z; d[3] = a.w;
    d[4] = b.x; d[5] = b.y; d[6] = b.z; d[7] = b.w;
}
__device__ inline void load8(const __hip_bfloat16* p, float* d) {
    uint4 u = *(const uint4*)p;
    const __hip_bfloat16* h = (const __hip_bfloat16*)&u;
    #pragma unroll
    for (int i = 0; i < 8; i++) d[i] = __bfloat162float(h[i]);
}
__device__ inline void store1(float* o, float v)            { *o = v; }
__device__ inline void store1(__hip_bfloat16* o, float v)   { *o = __float2bfloat16(v); }

// ---------------------------------------------------------------------------
// NT GEMM: C[M,N] = A[M,K] * W[N,K]^T, fp32 accum.
// MODE 0: out[m*N + n]                      (row-major)
// MODE 1: out[((b*H+h)*S + s)*DH + dh]      (q/k/v head-major layout)
// ---------------------------------------------------------------------------
template<int MODE, typename TA, typename TW, typename TO>
__global__ __launch_bounds__(256)
void gemm_nt(const TA* __restrict__ A, const TW* __restrict__ W,
             TO* __restrict__ out, int M, int N, int K)
{
    const int BK = 32;
    __shared__ float As[64][33];   // +1 pad breaks bank conflicts
    __shared__ float Bs[64][33];

    const int m0 = blockIdx.y * 64;
    const int n0 = blockIdx.x * 64;
    const int tid = threadIdx.x;
    const int tx = tid & 15;
    const int ty = tid >> 4;

    float acc[4][4] = {};

    for (int k0 = 0; k0 < K; k0 += BK) {
        const int r = tid >> 2;          // 0..63
        const int c = (tid & 3) * 8;     // 0,8,16,24
        float tmp[8];
        load8(A + (size_t)(m0 + r) * K + k0 + c, tmp);
        #pragma unroll
        for (int i = 0; i < 8; i++) As[r][c + i] = tmp[i];
        load8(W + (size_t)(n0 + r) * K + k0 + c, tmp);
        #pragma unroll
        for (int i = 0; i < 8; i++) Bs[r][c + i] = tmp[i];
        __syncthreads();

        #pragma unroll
        for (int kk = 0; kk < BK; kk++) {
            float a[4], b[4];
            #pragma unroll
            for (int i = 0; i < 4; i++) a[i] = As[ty * 4 + i][kk];
            #pragma unroll
            for (int j = 0; j < 4; j++) b[j] = Bs[tx * 4 + j][kk];
            #pragma unroll
            for (int i = 0; i < 4; i++)
                #pragma unroll
                for (int j = 0; j < 4; j++)
                    acc[i][j] += a[i] * b[j];
        }
        __syncthreads();
    }

    #pragma unroll
    for (int i = 0; i < 4; i++) {
        const int m = m0 + ty * 4 + i;
        #pragma unroll
        for (int j = 0; j < 4; j++) {
            const int n = n0 + tx * 4 + j;
            size_t idx;
            if (MODE == 0) {
                idx = (size_t)m * N + n;
            } else {
                const int b  = m / S_, s  = m % S_;
                const int h  = n / DH_, dh = n % DH_;
                idx = (((size_t)(b * H_ + h)) * S_ + s) * DH_ + dh;
            }
            store1(out + idx, acc[i][j]);
        }
    }
}

// ---------------------------------------------------------------------------
// RoPE in-place on bf16 [B*H*S, DH] rows; cos/sin are fp32 [S, DH].
// ---------------------------------------------------------------------------
__global__ __launch_bounds__(256)
void rope_kernel(__hip_bfloat16* __restrict__ q,
                 const float* __restrict__ cos_,
                 const float* __restrict__ sin_)
{
    const size_t i = (size_t)blockIdx.x * blockDim.x + threadIdx.x;
    const int dh = (int)(i & 63);
    const size_t row = i >> 6;            // [0, B*H*S)
    const int s = (int)(row % S_);
    __hip_bfloat16* p = q + row * DH_;

    const float x1 = __bfloat162float(p[dh]);
    const float x2 = __bfloat162float(p[dh + 64]);
    const float c1 = cos_[s * DH_ + dh];
    const float s1 = sin_[s * DH_ + dh];
    const float c2 = cos_[s * DH_ + dh + 64];
    const float s2 = sin_[s * DH_ + dh + 64];

    p[dh]      = __float2bfloat16(x1 * c1 - x2 * s1);
    p[dh + 64] = __float2bfloat16(x2 * c2 + x1 * s2);
}

// ---------------------------------------------------------------------------
// Causal attention, one block (128 threads) per (bh, q_row).
// q,k,v bf16 in [B*H, S, DH]; vals written bf16 in [B, S, H, DH].
// ---------------------------------------------------------------------------
__global__ __launch_bounds__(128)
void attn_kernel(const __hip_bfloat16* __restrict__ q,
                 const __hip_bfloat16* __restrict__ k,
                 const __hip_bfloat16* __restrict__ v,
                 __hip_bfloat16* __restrict__ vals)
{
    __shared__ float sc[S_];
    __shared__ float ql[DH_];
    __shared__ float red[2];

    const int bid = blockIdx.x;          // bh*S + qs
    const int qs  = bid & (S_ - 1);
    const int bh  = bid >> 11;           // S_ = 2^11
    const int tid = threadIdx.x;

    const __hip_bfloat16* qp = q + ((size_t)bh * S_ + qs) * DH_;
    ql[tid] = __bfloat162float(qp[tid]);
    __syncthreads();

    const int nk = qs + 1;
    const float scale = 0.08838834764831845f;   // 1/sqrt(128)

    // ---- phase A: scores + local max --------------------------------------
    float lmax = -1e30f;
    for (int j = tid; j < nk; j += 128) {
        const __hip_bfloat16* kp = k + ((size_t)bh * S_ + j) * DH_;
        float dot = 0.f;
        #pragma unroll
        for (int c = 0; c < DH_ / 8; c++) {
            float kk[8];
            load8(kp + c * 8, kk);
            #pragma unroll
            for (int t = 0; t < 8; t++)
                dot += ql[c * 8 + t] * kk[t];
        }
        dot *= scale;
        sc[j] = dot;
        lmax = fmaxf(lmax, dot);
    }
    #pragma unroll
    for (int off = 32; off; off >>= 1)
        lmax = fmaxf(lmax, __shfl_down(lmax, off, 64));
    if ((tid & 63) == 0) red[tid >> 6] = lmax;
    __syncthreads();
    const float m = fmaxf(red[0], red[1]);

    // ---- phase B: exp + local sum -----------------------------------------
    float lsum = 0.f;
    for (int j = tid; j < nk; j += 128) {
        const float p = __expf(sc[j] - m);
        sc[j] = p;
        lsum += p;
    }
    #pragma unroll
    for (int off = 32; off; off >>= 1)
        lsum += __shfl_down(lsum, off, 64);
    __syncthreads();                       // all sc[] written; m consumed
    if ((tid & 63) == 0) red[tid >> 6] = lsum;
    __syncthreads();
    const float denom = red[0] + red[1];

    // ---- phase C: out[dh] = sum_j p_j * v[j][dh] --------------------------
    float acc = 0.f;
    const __hip_bfloat16* vp = v + (size_t)bh * S_ * DH_ + tid;
    for (int j = 0; j < nk; j++)
        acc += sc[j] * __bfloat162float(vp[(size_t)j * DH_]);

    const int b = bh >> 4, h = bh & 15;
    vals[(((size_t)b * S_ + qs) * H_ + h) * DH_ + tid] =
        __float2bfloat16(acc / denom);
}

// ---------------------------------------------------------------------------
extern "C" void kernel_launch(void* const* d_in, const int* in_sizes, int n_in,
                              void* d_out, int out_size, void* d_ws, size_t ws_size,
                              hipStream_t stream)
{
    const float* x    = (const float*)d_in[0];
    const float* cos_ = (const float*)d_in[1];
    const float* sin_ = (const float*)d_in[2];
    const float* Wq   = (const float*)d_in[3];
    const float* Wk   = (const float*)d_in[4];
    const float* Wv   = (const float*)d_in[5];
    const float* Wo   = (const float*)d_in[6];
    float* out = (float*)d_out;

    const size_t NELEM = (size_t)B_ * S_ * D_;       // 8388608
    __hip_bfloat16* q    = (__hip_bfloat16*)d_ws;
    __hip_bfloat16* k    = q + NELEM;
    __hip_bfloat16* v    = k + NELEM;
    __hip_bfloat16* vals = v + NELEM;

    const int M = B_ * S_, N = D_, K = D_;
    dim3 gg(N / 64, M / 64), bb(256);

    gemm_nt<1><<<gg, bb, 0, stream>>>(x, Wq, q, M, N, K);
    gemm_nt<1><<<gg, bb, 0, stream>>>(x, Wk, k, M, N, K);
    gemm_nt<1><<<gg, bb, 0, stream>>>(x, Wv, v, M, N, K);

    const int rope_threads = B_ * H_ * S_ * 64;      // 4194304
    rope_kernel<<<rope_threads / 256, 256, 0, stream>>>(q, cos_, sin_);
    rope_kernel<<<rope_threads / 256, 256, 0, stream>>>(k, cos_, sin_);

    attn_kernel<<<B_ * H_ * S_, 128, 0, stream>>>(q, k, v, vals);

    gemm_nt<0><<<gg, bb, 0, stream>>>(vals, Wo, out, M, N, K);
}

// Round 3
// 2994.926 us; speedup vs baseline: 2.3464x; 2.3464x over previous
//
#include <hip/hip_runtime.h>
#include <hip/hip_bf16.h>

#define B_  2
#define S_  2048
#define D_  2048
#define H_  16
#define DH_ 128

typedef __attribute__((ext_vector_type(8))) short bf16x8;
typedef __attribute__((ext_vector_type(4))) float f32x4;

// ---- typed helpers --------------------------------------------------------
__device__ inline void load8(const float* p, float* d) {
    float4 a = *(const float4*)p;
    float4 b = *(const float4*)(p + 4);
    d[0] = a.x; d[1] = a.y; d[2] = a.z; d[3] = a.w;
    d[4] = b.x; d[5] = b.y; d[6] = b.z; d[7] = b.w;
}
__device__ inline void load8(const __hip_bfloat16* p, float* d) {
    uint4 u = *(const uint4*)p;
    const __hip_bfloat16* h = (const __hip_bfloat16*)&u;
    #pragma unroll
    for (int i = 0; i < 8; i++) d[i] = __bfloat162float(h[i]);
}
__device__ inline void store1(float* o, float v)            { *o = v; }
__device__ inline void store1(__hip_bfloat16* o, float v)   { *o = __float2bfloat16(v); }
__device__ inline short bf16bits(float v) {
    __hip_bfloat16 h = __float2bfloat16(v);
    return *reinterpret_cast<short*>(&h);
}

// ---------------------------------------------------------------------------
// NT GEMM: C[M,N] = A[M,K] * W[N,K]^T, fp32 accum.
// MODE 0: out[m*N + n]                      (row-major)
// MODE 1: out[((b*H+h)*S + s)*DH + dh]      (q/k head-major [BH,S,DH])
// MODE 2: out[((b*H+h)*DH + dh)*S + s]      (v transposed   [BH,DH,S])
// ---------------------------------------------------------------------------
template<int MODE, typename TA, typename TW, typename TO>
__global__ __launch_bounds__(256)
void gemm_nt(const TA* __restrict__ A, const TW* __restrict__ W,
             TO* __restrict__ out, int M, int N, int K)
{
    const int BK = 32;
    __shared__ float As[64][33];
    __shared__ float Bs[64][33];

    const int m0 = blockIdx.y * 64;
    const int n0 = blockIdx.x * 64;
    const int tid = threadIdx.x;
    const int tx = tid & 15;
    const int ty = tid >> 4;

    float acc[4][4] = {};

    for (int k0 = 0; k0 < K; k0 += BK) {
        const int r = tid >> 2;
        const int c = (tid & 3) * 8;
        float tmp[8];
        load8(A + (size_t)(m0 + r) * K + k0 + c, tmp);
        #pragma unroll
        for (int i = 0; i < 8; i++) As[r][c + i] = tmp[i];
        load8(W + (size_t)(n0 + r) * K + k0 + c, tmp);
        #pragma unroll
        for (int i = 0; i < 8; i++) Bs[r][c + i] = tmp[i];
        __syncthreads();

        #pragma unroll
        for (int kk = 0; kk < BK; kk++) {
            float a[4], b[4];
            #pragma unroll
            for (int i = 0; i < 4; i++) a[i] = As[ty * 4 + i][kk];
            #pragma unroll
            for (int j = 0; j < 4; j++) b[j] = Bs[tx * 4 + j][kk];
            #pragma unroll
            for (int i = 0; i < 4; i++)
                #pragma unroll
                for (int j = 0; j < 4; j++)
                    acc[i][j] += a[i] * b[j];
        }
        __syncthreads();
    }

    #pragma unroll
    for (int i = 0; i < 4; i++) {
        const int m = m0 + ty * 4 + i;
        #pragma unroll
        for (int j = 0; j < 4; j++) {
            const int n = n0 + tx * 4 + j;
            size_t idx;
            if (MODE == 0) {
                idx = (size_t)m * N + n;
            } else if (MODE == 1) {
                const int b  = m / S_, s  = m % S_;
                const int h  = n / DH_, dh = n % DH_;
                idx = (((size_t)(b * H_ + h)) * S_ + s) * DH_ + dh;
            } else {
                const int b  = m / S_, s  = m % S_;
                const int h  = n / DH_, dh = n % DH_;
                idx = (((size_t)(b * H_ + h)) * DH_ + dh) * S_ + s;
            }
            store1(out + idx, acc[i][j]);
        }
    }
}

// ---------------------------------------------------------------------------
// RoPE in-place on bf16 [B*H*S, DH] rows; cos/sin are fp32 [S, DH].
// ---------------------------------------------------------------------------
__global__ __launch_bounds__(256)
void rope_kernel(__hip_bfloat16* __restrict__ q,
                 const float* __restrict__ cos_,
                 const float* __restrict__ sin_)
{
    const size_t i = (size_t)blockIdx.x * blockDim.x + threadIdx.x;
    const int dh = (int)(i & 63);
    const size_t row = i >> 6;
    const int s = (int)(row % S_);
    __hip_bfloat16* p = q + row * DH_;

    const float x1 = __bfloat162float(p[dh]);
    const float x2 = __bfloat162float(p[dh + 64]);
    const float c1 = cos_[s * DH_ + dh];
    const float s1 = sin_[s * DH_ + dh];
    const float c2 = cos_[s * DH_ + dh + 64];
    const float s2 = sin_[s * DH_ + dh + 64];

    p[dh]      = __float2bfloat16(x1 * c1 - x2 * s1);
    p[dh + 64] = __float2bfloat16(x2 * c2 + x1 * s2);
}

// ---------------------------------------------------------------------------
// Flash attention with MFMA 16x16x32 bf16.
// Block: 256 thr (4 waves). Q-tile 64 (16 rows/wave). kv-tile 64.
// q,k: [BH, S, DH]; vt: [BH, DH, S]; vals out: [B, S, H, DH].
// ---------------------------------------------------------------------------
#define KSTR 136   // 128 + 8 pad (keeps 16B align, breaks bank aliasing)
#define VSTR 72    // 64 + 8 pad
#define PSTR 72

__global__ __launch_bounds__(256)
void attn_mfma(const __hip_bfloat16* __restrict__ q,
               const __hip_bfloat16* __restrict__ k,
               const __hip_bfloat16* __restrict__ vt,
               __hip_bfloat16* __restrict__ vals)
{
    __shared__ __align__(16) short sK[64 * KSTR];     // 17.0 KB
    __shared__ __align__(16) short sV[128 * VSTR];    // 18.0 KB
    __shared__ __align__(16) short sP[4 * 16 * PSTR]; //  9.0 KB

    const int bh    = blockIdx.y;
    const int qtile = (int)(gridDim.x - 1) - (int)blockIdx.x;  // big blocks first
    const int q0    = qtile * 64;
    const int tid   = threadIdx.x;
    const int w     = tid >> 6;
    const int lane  = tid & 63;
    const int l15   = lane & 15;
    const int quad  = lane >> 4;
    const int qb    = q0 + w * 16;          // this wave's first q row

    // ---- Q fragments (A-layout): Q[qb+l15][quad*8 + c*32 + j] -------------
    bf16x8 qf[4];
    const __hip_bfloat16* qrow = q + ((size_t)bh * S_ + qb + l15) * DH_ + quad * 8;
    #pragma unroll
    for (int c = 0; c < 4; c++)
        qf[c] = *(const bf16x8*)(qrow + c * 32);

    f32x4 o[8];
    #pragma unroll
    for (int d = 0; d < 8; d++) o[d] = (f32x4)(0.0f);
    float mrow[4] = {-1e30f, -1e30f, -1e30f, -1e30f};
    float lrow[4] = {0.f, 0.f, 0.f, 0.f};

    const float scale = 0.08838834764831845f;   // 1/sqrt(128)

    for (int kv0 = 0; kv0 <= q0; kv0 += 64) {
        // ---- stage K tile: sK[r][0..127] ----------------------------------
        {
            const int r = tid >> 2, cb = (tid & 3) * 32;
            const __hip_bfloat16* kg = k + ((size_t)bh * S_ + kv0 + r) * DH_ + cb;
            short* dst = &sK[r * KSTR + cb];
            #pragma unroll
            for (int u = 0; u < 4; u++)
                *(uint4*)(dst + u * 8) = *(const uint4*)(kg + u * 8);
        }
        // ---- stage Vt tile: sV[d][0..63] ----------------------------------
        {
            const int r = tid >> 1, cb = (tid & 1) * 32;
            const __hip_bfloat16* vg = vt + ((size_t)bh * DH_ + r) * S_ + kv0 + cb;
            short* dst = &sV[r * VSTR + cb];
            #pragma unroll
            for (int u = 0; u < 4; u++)
                *(uint4*)(dst + u * 8) = *(const uint4*)(vg + u * 8);
        }
        __syncthreads();

        // ---- S = Q K^T : 4 n-tiles x 4 k-chunks ---------------------------
        f32x4 s[4];
        #pragma unroll
        for (int n = 0; n < 4; n++) s[n] = (f32x4)(0.0f);
        #pragma unroll
        for (int n = 0; n < 4; n++) {
            const short* kp = &sK[(n * 16 + l15) * KSTR + quad * 8];
            #pragma unroll
            for (int c = 0; c < 4; c++) {
                bf16x8 kf = *(const bf16x8*)(kp + c * 32);
                s[n] = __builtin_amdgcn_mfma_f32_16x16x32_bf16(qf[c], kf, s[n], 0, 0, 0);
            }
        }

        // ---- scale + causal mask ------------------------------------------
        const bool diag = (kv0 == q0);
        float sv[4][4];   // [ntile][reg]
        #pragma unroll
        for (int n = 0; n < 4; n++)
            #pragma unroll
            for (int r = 0; r < 4; r++) {
                float x = s[n][r] * scale;
                if (diag) {
                    const int kvg = kv0 + n * 16 + l15;
                    const int qg  = qb + quad * 4 + r;
                    if (kvg > qg) x = -1e30f;
                }
                sv[n][r] = x;
            }

        // ---- row max (reduce over 16 lanes holding the row) ---------------
        float rmax[4];
        #pragma unroll
        for (int r = 0; r < 4; r++) {
            float v = fmaxf(fmaxf(sv[0][r], sv[1][r]), fmaxf(sv[2][r], sv[3][r]));
            #pragma unroll
            for (int msk = 8; msk; msk >>= 1)
                v = fmaxf(v, __shfl_xor(v, msk, 64));
            rmax[r] = v;
        }

        // ---- online softmax update ----------------------------------------
        float alpha[4];
        #pragma unroll
        for (int r = 0; r < 4; r++) {
            const float mn = fmaxf(mrow[r], rmax[r]);
            alpha[r] = __expf(mrow[r] - mn);
            mrow[r] = mn;
        }
        float rsum[4] = {0.f, 0.f, 0.f, 0.f};
        #pragma unroll
        for (int n = 0; n < 4; n++)
            #pragma unroll
            for (int r = 0; r < 4; r++) {
                const float p = __expf(sv[n][r] - mrow[r]);
                sv[n][r] = p;
                rsum[r] += p;
            }
        #pragma unroll
        for (int r = 0; r < 4; r++) {
            float v = rsum[r];
            #pragma unroll
            for (int msk = 8; msk; msk >>= 1)
                v += __shfl_xor(v, msk, 64);
            lrow[r] = lrow[r] * alpha[r] + v;
        }
        #pragma unroll
        for (int d = 0; d < 8; d++)
            #pragma unroll
            for (int r = 0; r < 4; r++)
                o[d][r] *= alpha[r];

        // ---- P: C-layout -> LDS -> A-layout -------------------------------
        short* pb = &sP[w * 16 * PSTR];
        #pragma unroll
        for (int n = 0; n < 4; n++)
            #pragma unroll
            for (int r = 0; r < 4; r++)
                pb[(quad * 4 + r) * PSTR + n * 16 + l15] = bf16bits(sv[n][r]);

        // ---- O += P V : 2 k-chunks x 8 d-tiles ----------------------------
        #pragma unroll
        for (int c = 0; c < 2; c++) {
            bf16x8 pf = *(const bf16x8*)(&pb[l15 * PSTR + c * 32 + quad * 8]);
            #pragma unroll
            for (int d = 0; d < 8; d++) {
                bf16x8 vf = *(const bf16x8*)(&sV[(d * 16 + l15) * VSTR + c * 32 + quad * 8]);
                o[d] = __builtin_amdgcn_mfma_f32_16x16x32_bf16(pf, vf, o[d], 0, 0, 0);
            }
        }
        __syncthreads();
    }

    // ---- epilogue: normalize, store to vals [B,S,H,DH] --------------------
    const int b = bh >> 4, h = bh & 15;
    #pragma unroll
    for (int r = 0; r < 4; r++) {
        const int qg = qb + quad * 4 + r;
        const float inv = 1.0f / lrow[r];
        #pragma unroll
        for (int d = 0; d < 8; d++) {
            const int col = d * 16 + l15;
            vals[(((size_t)b * S_ + qg) * H_ + h) * DH_ + col] =
                __float2bfloat16(o[d][r] * inv);
        }
    }
}

// ---------------------------------------------------------------------------
extern "C" void kernel_launch(void* const* d_in, const int* in_sizes, int n_in,
                              void* d_out, int out_size, void* d_ws, size_t ws_size,
                              hipStream_t stream)
{
    const float* x    = (const float*)d_in[0];
    const float* cos_ = (const float*)d_in[1];
    const float* sin_ = (const float*)d_in[2];
    const float* Wq   = (const float*)d_in[3];
    const float* Wk   = (const float*)d_in[4];
    const float* Wv   = (const float*)d_in[5];
    const float* Wo   = (const float*)d_in[6];
    float* out = (float*)d_out;

    const size_t NELEM = (size_t)B_ * S_ * D_;       // 8388608
    __hip_bfloat16* q    = (__hip_bfloat16*)d_ws;
    __hip_bfloat16* k    = q + NELEM;
    __hip_bfloat16* vt   = k + NELEM;                // [BH, DH, S]
    __hip_bfloat16* vals = vt + NELEM;

    const int M = B_ * S_, N = D_, K = D_;
    dim3 gg(N / 64, M / 64), bb(256);

    gemm_nt<1><<<gg, bb, 0, stream>>>(x, Wq, q, M, N, K);
    gemm_nt<1><<<gg, bb, 0, stream>>>(x, Wk, k, M, N, K);
    gemm_nt<2><<<gg, bb, 0, stream>>>(x, Wv, vt, M, N, K);

    const int rope_threads = B_ * H_ * S_ * 64;
    rope_kernel<<<rope_threads / 256, 256, 0, stream>>>(q, cos_, sin_);
    rope_kernel<<<rope_threads / 256, 256, 0, stream>>>(k, cos_, sin_);

    attn_mfma<<<dim3(S_ / 64, B_ * H_), 256, 0, stream>>>(q, k, vt, vals);

    gemm_nt<0><<<gg, bb, 0, stream>>>(vals, Wo, out, M, N, K);
}

// Round 4
// 618.605 us; speedup vs baseline: 11.3599x; 4.8414x over previous
//
#include <hip/hip_runtime.h>
#include <hip/hip_bf16.h>

#define B_  2
#define S_  2048
#define D_  2048
#define H_  16
#define DH_ 128

typedef __attribute__((ext_vector_type(8))) short bf16x8;
typedef __attribute__((ext_vector_type(4))) float f32x4;

__device__ inline short bf16bits(float v) {
    __hip_bfloat16 h = __float2bfloat16(v);
    return *reinterpret_cast<short*>(&h);
}

// ---------------------------------------------------------------------------
// fp32 -> bf16 cast, 8 elements/thread, vectorized.
// ---------------------------------------------------------------------------
__global__ __launch_bounds__(256)
void f2b_kernel(const float* __restrict__ in, __hip_bfloat16* __restrict__ out)
{
    const size_t i = ((size_t)blockIdx.x * 256 + threadIdx.x) * 8;
    float4 a = *(const float4*)(in + i);
    float4 b = *(const float4*)(in + i + 4);
    short s[8] = { bf16bits(a.x), bf16bits(a.y), bf16bits(a.z), bf16bits(a.w),
                   bf16bits(b.x), bf16bits(b.y), bf16bits(b.z), bf16bits(b.w) };
    *(uint4*)(out + i) = *(const uint4*)s;
}

// ---------------------------------------------------------------------------
// MFMA NT GEMM (m97 structure): C[M,N] = A[M,K] * W[N,K]^T, bf16 in, fp32 acc.
// 128x128 tile, BK=32, global_load_lds 16B staging, 4 waves, 64x64 per wave.
// MODE 0: out[m*N + n]                   MODE 1: q/k head-major [BH,S,DH]
// MODE 2: v transposed [BH,DH,S]
// ---------------------------------------------------------------------------
#define BKg 32

__device__ inline void async16(const __hip_bfloat16* g, short* l) {
    __builtin_amdgcn_global_load_lds(
        (const __attribute__((address_space(1))) void*)g,
        (__attribute__((address_space(3))) void*)l, 16, 0, 0);
}

template<int MODE, typename TO>
__global__ __launch_bounds__(256)
void gemm_mfma(const __hip_bfloat16* __restrict__ A,
               const __hip_bfloat16* __restrict__ W,
               TO* __restrict__ out, int M, int N, int K)
{
    __shared__ __align__(16) short sA[128 * BKg];   // 8 KB, unpadded (lds-dma layout)
    __shared__ __align__(16) short sB[128 * BKg];   // 8 KB

    const int tid  = threadIdx.x;
    const int w    = tid >> 6;
    const int lane = tid & 63;
    const int l15  = lane & 15;
    const int quad = lane >> 4;

    const int m0 = blockIdx.y * 128;
    const int n0 = blockIdx.x * 128;

    // staging: wave w, iter t covers rows [w*32 + t*16, +16), lane>>2 row, (lane&3)*8 col
    const int sr0 = w * 32 + (lane >> 2);
    const int scol = (lane & 3) * 8;

    const int wm = (w >> 1) * 64;
    const int wn = (w & 1) * 64;

    f32x4 acc[4][4];
    #pragma unroll
    for (int i = 0; i < 4; i++)
        #pragma unroll
        for (int j = 0; j < 4; j++) acc[i][j] = (f32x4)(0.0f);

    for (int k0 = 0; k0 < K; k0 += BKg) {
        #pragma unroll
        for (int t = 0; t < 2; t++) {
            const int r = sr0 + t * 16;
            async16(A + (size_t)(m0 + r) * K + k0 + scol, sA + (w * 2 + t) * 512);
            async16(W + (size_t)(n0 + r) * K + k0 + scol, sB + (w * 2 + t) * 512);
        }
        __syncthreads();

        bf16x8 af[4], bf[4];
        #pragma unroll
        for (int i = 0; i < 4; i++)
            af[i] = *(const bf16x8*)(sA + (wm + i * 16 + l15) * BKg + quad * 8);
        #pragma unroll
        for (int j = 0; j < 4; j++)
            bf[j] = *(const bf16x8*)(sB + (wn + j * 16 + l15) * BKg + quad * 8);
        #pragma unroll
        for (int i = 0; i < 4; i++)
            #pragma unroll
            for (int j = 0; j < 4; j++)
                acc[i][j] = __builtin_amdgcn_mfma_f32_16x16x32_bf16(af[i], bf[j], acc[i][j], 0, 0, 0);
        __syncthreads();
    }

    #pragma unroll
    for (int i = 0; i < 4; i++) {
        #pragma unroll
        for (int r = 0; r < 4; r++) {
            const int m = m0 + wm + i * 16 + quad * 4 + r;
            #pragma unroll
            for (int j = 0; j < 4; j++) {
                const int n = n0 + wn + j * 16 + l15;
                size_t idx;
                if (MODE == 0) {
                    idx = (size_t)m * N + n;
                } else if (MODE == 1) {
                    const int b  = m / S_, s  = m % S_;
                    const int h  = n / DH_, dh = n % DH_;
                    idx = (((size_t)(b * H_ + h)) * S_ + s) * DH_ + dh;
                } else {
                    const int b  = m / S_, s  = m % S_;
                    const int h  = n / DH_, dh = n % DH_;
                    idx = (((size_t)(b * H_ + h)) * DH_ + dh) * S_ + s;
                }
                if (MODE == 0) ((float*)out)[idx] = acc[i][j][r];
                else ((__hip_bfloat16*)out)[idx] = __float2bfloat16(acc[i][j][r]);
            }
        }
    }
}

// ---------------------------------------------------------------------------
// RoPE in-place on bf16 [B*H*S, DH] rows; cos/sin are fp32 [S, DH].
// ---------------------------------------------------------------------------
__global__ __launch_bounds__(256)
void rope_kernel(__hip_bfloat16* __restrict__ q,
                 const float* __restrict__ cos_,
                 const float* __restrict__ sin_)
{
    const size_t i = (size_t)blockIdx.x * blockDim.x + threadIdx.x;
    const int dh = (int)(i & 63);
    const size_t row = i >> 6;
    const int s = (int)(row % S_);
    __hip_bfloat16* p = q + row * DH_;

    const float x1 = __bfloat162float(p[dh]);
    const float x2 = __bfloat162float(p[dh + 64]);
    const float c1 = cos_[s * DH_ + dh];
    const float s1 = sin_[s * DH_ + dh];
    const float c2 = cos_[s * DH_ + dh + 64];
    const float s2 = sin_[s * DH_ + dh + 64];

    p[dh]      = __float2bfloat16(x1 * c1 - x2 * s1);
    p[dh + 64] = __float2bfloat16(x2 * c2 + x1 * s2);
}

// ---------------------------------------------------------------------------
// Flash attention with MFMA 16x16x32 bf16 (validated round 2).
// ---------------------------------------------------------------------------
#define KSTR 136
#define VSTR 72
#define PSTR 72

__global__ __launch_bounds__(256)
void attn_mfma(const __hip_bfloat16* __restrict__ q,
               const __hip_bfloat16* __restrict__ k,
               const __hip_bfloat16* __restrict__ vt,
               __hip_bfloat16* __restrict__ vals)
{
    __shared__ __align__(16) short sK[64 * KSTR];
    __shared__ __align__(16) short sV[128 * VSTR];
    __shared__ __align__(16) short sP[4 * 16 * PSTR];

    const int bh    = blockIdx.y;
    const int qtile = (int)(gridDim.x - 1) - (int)blockIdx.x;
    const int q0    = qtile * 64;
    const int tid   = threadIdx.x;
    const int w     = tid >> 6;
    const int lane  = tid & 63;
    const int l15   = lane & 15;
    const int quad  = lane >> 4;
    const int qb    = q0 + w * 16;

    bf16x8 qf[4];
    const __hip_bfloat16* qrow = q + ((size_t)bh * S_ + qb + l15) * DH_ + quad * 8;
    #pragma unroll
    for (int c = 0; c < 4; c++)
        qf[c] = *(const bf16x8*)(qrow + c * 32);

    f32x4 o[8];
    #pragma unroll
    for (int d = 0; d < 8; d++) o[d] = (f32x4)(0.0f);
    float mrow[4] = {-1e30f, -1e30f, -1e30f, -1e30f};
    float lrow[4] = {0.f, 0.f, 0.f, 0.f};

    const float scale = 0.08838834764831845f;

    for (int kv0 = 0; kv0 <= q0; kv0 += 64) {
        {
            const int r = tid >> 2, cb = (tid & 3) * 32;
            const __hip_bfloat16* kg = k + ((size_t)bh * S_ + kv0 + r) * DH_ + cb;
            short* dst = &sK[r * KSTR + cb];
            #pragma unroll
            for (int u = 0; u < 4; u++)
                *(uint4*)(dst + u * 8) = *(const uint4*)(kg + u * 8);
        }
        {
            const int r = tid >> 1, cb = (tid & 1) * 32;
            const __hip_bfloat16* vg = vt + ((size_t)bh * DH_ + r) * S_ + kv0 + cb;
            short* dst = &sV[r * VSTR + cb];
            #pragma unroll
            for (int u = 0; u < 4; u++)
                *(uint4*)(dst + u * 8) = *(const uint4*)(vg + u * 8);
        }
        __syncthreads();

        f32x4 s[4];
        #pragma unroll
        for (int n = 0; n < 4; n++) s[n] = (f32x4)(0.0f);
        #pragma unroll
        for (int n = 0; n < 4; n++) {
            const short* kp = &sK[(n * 16 + l15) * KSTR + quad * 8];
            #pragma unroll
            for (int c = 0; c < 4; c++) {
                bf16x8 kf = *(const bf16x8*)(kp + c * 32);
                s[n] = __builtin_amdgcn_mfma_f32_16x16x32_bf16(qf[c], kf, s[n], 0, 0, 0);
            }
        }

        const bool diag = (kv0 == q0);
        float sv[4][4];
        #pragma unroll
        for (int n = 0; n < 4; n++)
            #pragma unroll
            for (int r = 0; r < 4; r++) {
                float x = s[n][r] * scale;
                if (diag) {
                    const int kvg = kv0 + n * 16 + l15;
                    const int qg  = qb + quad * 4 + r;
                    if (kvg > qg) x = -1e30f;
                }
                sv[n][r] = x;
            }

        float rmax[4];
        #pragma unroll
        for (int r = 0; r < 4; r++) {
            float v = fmaxf(fmaxf(sv[0][r], sv[1][r]), fmaxf(sv[2][r], sv[3][r]));
            #pragma unroll
            for (int msk = 8; msk; msk >>= 1)
                v = fmaxf(v, __shfl_xor(v, msk, 64));
            rmax[r] = v;
        }

        float alpha[4];
        #pragma unroll
        for (int r = 0; r < 4; r++) {
            const float mn = fmaxf(mrow[r], rmax[r]);
            alpha[r] = __expf(mrow[r] - mn);
            mrow[r] = mn;
        }
        float rsum[4] = {0.f, 0.f, 0.f, 0.f};
        #pragma unroll
        for (int n = 0; n < 4; n++)
            #pragma unroll
            for (int r = 0; r < 4; r++) {
                const float p = __expf(sv[n][r] - mrow[r]);
                sv[n][r] = p;
                rsum[r] += p;
            }
        #pragma unroll
        for (int r = 0; r < 4; r++) {
            float v = rsum[r];
            #pragma unroll
            for (int msk = 8; msk; msk >>= 1)
                v += __shfl_xor(v, msk, 64);
            lrow[r] = lrow[r] * alpha[r] + v;
        }
        #pragma unroll
        for (int d = 0; d < 8; d++)
            #pragma unroll
            for (int r = 0; r < 4; r++)
                o[d][r] *= alpha[r];

        short* pb = &sP[w * 16 * PSTR];
        #pragma unroll
        for (int n = 0; n < 4; n++)
            #pragma unroll
            for (int r = 0; r < 4; r++)
                pb[(quad * 4 + r) * PSTR + n * 16 + l15] = bf16bits(sv[n][r]);

        #pragma unroll
        for (int c = 0; c < 2; c++) {
            bf16x8 pf = *(const bf16x8*)(&pb[l15 * PSTR + c * 32 + quad * 8]);
            #pragma unroll
            for (int d = 0; d < 8; d++) {
                bf16x8 vf = *(const bf16x8*)(&sV[(d * 16 + l15) * VSTR + c * 32 + quad * 8]);
                o[d] = __builtin_amdgcn_mfma_f32_16x16x32_bf16(pf, vf, o[d], 0, 0, 0);
            }
        }
        __syncthreads();
    }

    const int b = bh >> 4, h = bh & 15;
    #pragma unroll
    for (int r = 0; r < 4; r++) {
        const int qg = qb + quad * 4 + r;
        const float inv = 1.0f / lrow[r];
        #pragma unroll
        for (int d = 0; d < 8; d++) {
            const int col = d * 16 + l15;
            vals[(((size_t)b * S_ + qg) * H_ + h) * DH_ + col] =
                __float2bfloat16(o[d][r] * inv);
        }
    }
}

// ---------------------------------------------------------------------------
extern "C" void kernel_launch(void* const* d_in, const int* in_sizes, int n_in,
                              void* d_out, int out_size, void* d_ws, size_t ws_size,
                              hipStream_t stream)
{
    const float* x    = (const float*)d_in[0];
    const float* cos_ = (const float*)d_in[1];
    const float* sin_ = (const float*)d_in[2];
    const float* Wq   = (const float*)d_in[3];
    const float* Wk   = (const float*)d_in[4];
    const float* Wv   = (const float*)d_in[5];
    const float* Wo   = (const float*)d_in[6];
    float* out = (float*)d_out;

    const size_t NELEM = (size_t)B_ * S_ * D_;       // 8388608
    const size_t WELEM = (size_t)D_ * D_;            // 4194304

    // scratch inside d_out (33.5 MB): xb [0,16.8M), wb [16.8M,25.2M)
    __hip_bfloat16* xb = (__hip_bfloat16*)d_out;
    __hip_bfloat16* wb = xb + NELEM;
    // ws: q,k,vt,vals (67 MB). Wo-bf16 reuses q after attention.
    __hip_bfloat16* q    = (__hip_bfloat16*)d_ws;
    __hip_bfloat16* k    = q + NELEM;
    __hip_bfloat16* vt   = k + NELEM;
    __hip_bfloat16* vals = vt + NELEM;
    __hip_bfloat16* wob  = q;

    const int M = B_ * S_, N = D_, K = D_;
    dim3 gg(N / 128, M / 128), bb(256);
    const int xcb = (int)(NELEM / (256 * 8));
    const int wcb = (int)(WELEM / (256 * 8));

    f2b_kernel<<<xcb, 256, 0, stream>>>(x, xb);
    f2b_kernel<<<wcb, 256, 0, stream>>>(Wq, wb);
    gemm_mfma<1, __hip_bfloat16><<<gg, bb, 0, stream>>>(xb, wb, q, M, N, K);
    f2b_kernel<<<wcb, 256, 0, stream>>>(Wk, wb);
    gemm_mfma<1, __hip_bfloat16><<<gg, bb, 0, stream>>>(xb, wb, k, M, N, K);
    f2b_kernel<<<wcb, 256, 0, stream>>>(Wv, wb);
    gemm_mfma<2, __hip_bfloat16><<<gg, bb, 0, stream>>>(xb, wb, vt, M, N, K);

    const int rope_threads = B_ * H_ * S_ * 64;
    rope_kernel<<<rope_threads / 256, 256, 0, stream>>>(q, cos_, sin_);
    rope_kernel<<<rope_threads / 256, 256, 0, stream>>>(k, cos_, sin_);

    attn_mfma<<<dim3(S_ / 64, B_ * H_), 256, 0, stream>>>(q, k, vt, vals);

    f2b_kernel<<<wcb, 256, 0, stream>>>(Wo, wob);
    gemm_mfma<0, float><<<gg, bb, 0, stream>>>(vals, wob, out, M, N, K);
}

// Round 5
// 612.988 us; speedup vs baseline: 11.4640x; 1.0092x over previous
//
#include <hip/hip_runtime.h>
#include <hip/hip_bf16.h>

#define B_  2
#define S_  2048
#define D_  2048
#define H_  16
#define DH_ 128

typedef __attribute__((ext_vector_type(8))) short bf16x8;
typedef __attribute__((ext_vector_type(4))) float f32x4;

__device__ inline short bf16bits(float v) {
    __hip_bfloat16 h = __float2bfloat16(v);
    return *reinterpret_cast<short*>(&h);
}

// ---------------------------------------------------------------------------
// fp32 -> bf16 cast, 8 elements/thread, vectorized.
// ---------------------------------------------------------------------------
__global__ __launch_bounds__(256)
void f2b_kernel(const float* __restrict__ in, __hip_bfloat16* __restrict__ out)
{
    const size_t i = ((size_t)blockIdx.x * 256 + threadIdx.x) * 8;
    float4 a = *(const float4*)(in + i);
    float4 b = *(const float4*)(in + i + 4);
    short s[8] = { bf16bits(a.x), bf16bits(a.y), bf16bits(a.z), bf16bits(a.w),
                   bf16bits(b.x), bf16bits(b.y), bf16bits(b.z), bf16bits(b.w) };
    *(uint4*)(out + i) = *(const uint4*)s;
}

// ---------------------------------------------------------------------------
// MFMA NT GEMM (m97 structure): C[M,N] = A[M,K] * W[N,K]^T, bf16 in, fp32 acc.
// ---------------------------------------------------------------------------
#define BKg 32

__device__ inline void async16(const __hip_bfloat16* g, short* l) {
    __builtin_amdgcn_global_load_lds(
        (const __attribute__((address_space(1))) void*)g,
        (__attribute__((address_space(3))) void*)l, 16, 0, 0);
}

template<int MODE, typename TO>
__global__ __launch_bounds__(256)
void gemm_mfma(const __hip_bfloat16* __restrict__ A,
               const __hip_bfloat16* __restrict__ W,
               TO* __restrict__ out, int M, int N, int K)
{
    __shared__ __align__(16) short sA[128 * BKg];
    __shared__ __align__(16) short sB[128 * BKg];

    const int tid  = threadIdx.x;
    const int w    = tid >> 6;
    const int lane = tid & 63;
    const int l15  = lane & 15;
    const int quad = lane >> 4;

    const int m0 = blockIdx.y * 128;
    const int n0 = blockIdx.x * 128;

    const int sr0 = w * 32 + (lane >> 2);
    const int scol = (lane & 3) * 8;

    const int wm = (w >> 1) * 64;
    const int wn = (w & 1) * 64;

    f32x4 acc[4][4];
    #pragma unroll
    for (int i = 0; i < 4; i++)
        #pragma unroll
        for (int j = 0; j < 4; j++) acc[i][j] = (f32x4)(0.0f);

    for (int k0 = 0; k0 < K; k0 += BKg) {
        #pragma unroll
        for (int t = 0; t < 2; t++) {
            const int r = sr0 + t * 16;
            async16(A + (size_t)(m0 + r) * K + k0 + scol, sA + (w * 2 + t) * 512);
            async16(W + (size_t)(n0 + r) * K + k0 + scol, sB + (w * 2 + t) * 512);
        }
        __syncthreads();

        bf16x8 af[4], bf[4];
        #pragma unroll
        for (int i = 0; i < 4; i++)
            af[i] = *(const bf16x8*)(sA + (wm + i * 16 + l15) * BKg + quad * 8);
        #pragma unroll
        for (int j = 0; j < 4; j++)
            bf[j] = *(const bf16x8*)(sB + (wn + j * 16 + l15) * BKg + quad * 8);
        #pragma unroll
        for (int i = 0; i < 4; i++)
            #pragma unroll
            for (int j = 0; j < 4; j++)
                acc[i][j] = __builtin_amdgcn_mfma_f32_16x16x32_bf16(af[i], bf[j], acc[i][j], 0, 0, 0);
        __syncthreads();
    }

    #pragma unroll
    for (int i = 0; i < 4; i++) {
        #pragma unroll
        for (int r = 0; r < 4; r++) {
            const int m = m0 + wm + i * 16 + quad * 4 + r;
            #pragma unroll
            for (int j = 0; j < 4; j++) {
                const int n = n0 + wn + j * 16 + l15;
                size_t idx;
                if (MODE == 0) {
                    idx = (size_t)m * N + n;
                } else if (MODE == 1) {
                    const int b  = m / S_, s  = m % S_;
                    const int h  = n / DH_, dh = n % DH_;
                    idx = (((size_t)(b * H_ + h)) * S_ + s) * DH_ + dh;
                } else {
                    const int b  = m / S_, s  = m % S_;
                    const int h  = n / DH_, dh = n % DH_;
                    idx = (((size_t)(b * H_ + h)) * DH_ + dh) * S_ + s;
                }
                if (MODE == 0) ((float*)out)[idx] = acc[i][j][r];
                else ((__hip_bfloat16*)out)[idx] = __float2bfloat16(acc[i][j][r]);
            }
        }
    }
}

// ---------------------------------------------------------------------------
// RoPE in-place on bf16 [B*H*S, DH] rows; cos/sin are fp32 [S, DH].
// ---------------------------------------------------------------------------
__global__ __launch_bounds__(256)
void rope_kernel(__hip_bfloat16* __restrict__ q,
                 const float* __restrict__ cos_,
                 const float* __restrict__ sin_)
{
    const size_t i = (size_t)blockIdx.x * blockDim.x + threadIdx.x;
    const int dh = (int)(i & 63);
    const size_t row = i >> 6;
    const int s = (int)(row % S_);
    __hip_bfloat16* p = q + row * DH_;

    const float x1 = __bfloat162float(p[dh]);
    const float x2 = __bfloat162float(p[dh + 64]);
    const float c1 = cos_[s * DH_ + dh];
    const float s1 = sin_[s * DH_ + dh];
    const float c2 = cos_[s * DH_ + dh + 64];
    const float s2 = sin_[s * DH_ + dh + 64];

    p[dh]      = __float2bfloat16(x1 * c1 - x2 * s1);
    p[dh + 64] = __float2bfloat16(x2 * c2 + x1 * s2);
}

// ---------------------------------------------------------------------------
// Flash attention v2: Q-tile 128 (32 rows/wave), kv-tile 64, register-prefetch
// double buffering, deferred l-reduction.
// q,k: [BH,S,DH]; vt: [BH,DH,S]; vals: [B,S,H,DH].
// ---------------------------------------------------------------------------
#define KSTR 136
#define VSTR 72
#define PSTR 72

__global__ __launch_bounds__(256)
void attn_mfma(const __hip_bfloat16* __restrict__ q,
               const __hip_bfloat16* __restrict__ k,
               const __hip_bfloat16* __restrict__ vt,
               __hip_bfloat16* __restrict__ vals)
{
    __shared__ __align__(16) short sK[64 * KSTR];      // 17.0 KB
    __shared__ __align__(16) short sV[128 * VSTR];     // 18.4 KB
    __shared__ __align__(16) short sP[4 * 32 * PSTR];  // 18.4 KB

    const int bh    = blockIdx.y;
    const int qtile = (int)(gridDim.x - 1) - (int)blockIdx.x;  // big first
    const int q0    = qtile * 128;
    const int tid   = threadIdx.x;
    const int w     = tid >> 6;
    const int lane  = tid & 63;
    const int l15   = lane & 15;
    const int quad  = lane >> 4;
    const int qb    = q0 + w * 32;          // wave's 32 q rows

    // ---- Q fragments (A-layout), 2 m-tiles ------------------------------
    bf16x8 qf[2][4];
    #pragma unroll
    for (int mi = 0; mi < 2; mi++) {
        const __hip_bfloat16* qrow =
            q + ((size_t)bh * S_ + qb + mi * 16 + l15) * DH_ + quad * 8;
        #pragma unroll
        for (int c = 0; c < 4; c++)
            qf[mi][c] = *(const bf16x8*)(qrow + c * 32);
    }

    f32x4 o[2][8];
    #pragma unroll
    for (int mi = 0; mi < 2; mi++)
        #pragma unroll
        for (int d = 0; d < 8; d++) o[mi][d] = (f32x4)(0.0f);
    float mrow[2][4], lrow[2][4];
    #pragma unroll
    for (int mi = 0; mi < 2; mi++)
        #pragma unroll
        for (int r = 0; r < 4; r++) { mrow[mi][r] = -1e30f; lrow[mi][r] = 0.f; }

    const float scale = 0.08838834764831845f;   // 1/sqrt(128)

    // staging assignment
    const int kr = tid >> 2, kc = (tid & 3) * 32;
    const int vr = tid >> 1, vc = (tid & 1) * 32;
    const int niter = qtile * 2 + 2;

    uint4 kreg[4], vreg[4];
    {
        const __hip_bfloat16* kg = k + ((size_t)bh * S_ + kr) * DH_ + kc;
        const __hip_bfloat16* vg = vt + ((size_t)bh * DH_ + vr) * S_ + vc;
        #pragma unroll
        for (int u = 0; u < 4; u++) kreg[u] = *(const uint4*)(kg + u * 8);
        #pragma unroll
        for (int u = 0; u < 4; u++) vreg[u] = *(const uint4*)(vg + u * 8);
    }

    for (int it = 0; it < niter; ++it) {
        const int kv0 = it * 64;

        // ---- staged regs -> LDS ------------------------------------------
        {
            short* dk = &sK[kr * KSTR + kc];
            #pragma unroll
            for (int u = 0; u < 4; u++) *(uint4*)(dk + u * 8) = kreg[u];
            short* dv = &sV[vr * VSTR + vc];
            #pragma unroll
            for (int u = 0; u < 4; u++) *(uint4*)(dv + u * 8) = vreg[u];
        }
        __syncthreads();

        // ---- prefetch next tile into regs (overlaps compute) -------------
        if (it + 1 < niter) {
            const int nv = kv0 + 64;
            const __hip_bfloat16* kg = k + ((size_t)bh * S_ + nv + kr) * DH_ + kc;
            const __hip_bfloat16* vg = vt + ((size_t)bh * DH_ + vr) * S_ + nv + vc;
            #pragma unroll
            for (int u = 0; u < 4; u++) kreg[u] = *(const uint4*)(kg + u * 8);
            #pragma unroll
            for (int u = 0; u < 4; u++) vreg[u] = *(const uint4*)(vg + u * 8);
        }

        if (kv0 <= qb + 31) {     // wave has unmasked work in this tile
            // ---- S = Q K^T (K-fragment reused across both m-tiles) -------
            f32x4 s[2][4];
            #pragma unroll
            for (int mi = 0; mi < 2; mi++)
                #pragma unroll
                for (int n = 0; n < 4; n++) s[mi][n] = (f32x4)(0.0f);
            #pragma unroll
            for (int n = 0; n < 4; n++) {
                const short* kp = &sK[(n * 16 + l15) * KSTR + quad * 8];
                #pragma unroll
                for (int c = 0; c < 4; c++) {
                    bf16x8 kf = *(const bf16x8*)(kp + c * 32);
                    s[0][n] = __builtin_amdgcn_mfma_f32_16x16x32_bf16(qf[0][c], kf, s[0][n], 0, 0, 0);
                    s[1][n] = __builtin_amdgcn_mfma_f32_16x16x32_bf16(qf[1][c], kf, s[1][n], 0, 0, 0);
                }
            }

            #pragma unroll
            for (int mi = 0; mi < 2; mi++) {
                const int qbm = qb + mi * 16;
                const bool msk = (kv0 + 63 > qbm);
                float sv[4][4];
                #pragma unroll
                for (int n = 0; n < 4; n++)
                    #pragma unroll
                    for (int r = 0; r < 4; r++) {
                        float x = s[mi][n][r] * scale;
                        if (msk) {
                            const int kvg = kv0 + n * 16 + l15;
                            const int qg  = qbm + quad * 4 + r;
                            if (kvg > qg) x = -1e30f;
                        }
                        sv[n][r] = x;
                    }

                // row max over 16 lanes
                float alpha[4];
                #pragma unroll
                for (int r = 0; r < 4; r++) {
                    float v = fmaxf(fmaxf(sv[0][r], sv[1][r]), fmaxf(sv[2][r], sv[3][r]));
                    #pragma unroll
                    for (int m2 = 8; m2; m2 >>= 1)
                        v = fmaxf(v, __shfl_xor(v, m2, 64));
                    const float mn = fmaxf(mrow[mi][r], v);
                    alpha[r] = __expf(mrow[mi][r] - mn);
                    mrow[mi][r] = mn;
                }
                // exp + per-lane partial l (reduced once in epilogue)
                #pragma unroll
                for (int r = 0; r < 4; r++) {
                    float rs = 0.f;
                    #pragma unroll
                    for (int n = 0; n < 4; n++) {
                        const float p = __expf(sv[n][r] - mrow[mi][r]);
                        sv[n][r] = p;
                        rs += p;
                    }
                    lrow[mi][r] = lrow[mi][r] * alpha[r] + rs;
                }
                #pragma unroll
                for (int d = 0; d < 8; d++)
                    #pragma unroll
                    for (int r = 0; r < 4; r++)
                        o[mi][d][r] *= alpha[r];

                // P: C-layout -> LDS (wave-private)
                short* pb = &sP[(w * 32 + mi * 16) * PSTR];
                #pragma unroll
                for (int n = 0; n < 4; n++)
                    #pragma unroll
                    for (int r = 0; r < 4; r++)
                        pb[(quad * 4 + r) * PSTR + n * 16 + l15] = bf16bits(sv[n][r]);
            }

            // ---- O += P V (V-fragment reused across both m-tiles) --------
            #pragma unroll
            for (int c = 0; c < 2; c++) {
                bf16x8 pf0 = *(const bf16x8*)(&sP[(w * 32 + l15) * PSTR + c * 32 + quad * 8]);
                bf16x8 pf1 = *(const bf16x8*)(&sP[(w * 32 + 16 + l15) * PSTR + c * 32 + quad * 8]);
                #pragma unroll
                for (int d = 0; d < 8; d++) {
                    bf16x8 vf = *(const bf16x8*)(&sV[(d * 16 + l15) * VSTR + c * 32 + quad * 8]);
                    o[0][d] = __builtin_amdgcn_mfma_f32_16x16x32_bf16(pf0, vf, o[0][d], 0, 0, 0);
                    o[1][d] = __builtin_amdgcn_mfma_f32_16x16x32_bf16(pf1, vf, o[1][d], 0, 0, 0);
                }
            }
        }
        __syncthreads();
    }

    // ---- epilogue: reduce l across lanes, normalize, store ---------------
    const int b = bh >> 4, h = bh & 15;
    #pragma unroll
    for (int mi = 0; mi < 2; mi++)
        #pragma unroll
        for (int r = 0; r < 4; r++) {
            float l = lrow[mi][r];
            #pragma unroll
            for (int m2 = 8; m2; m2 >>= 1)
                l += __shfl_xor(l, m2, 64);
            const float inv = 1.0f / l;
            const int qg = qb + mi * 16 + quad * 4 + r;
            #pragma unroll
            for (int d = 0; d < 8; d++) {
                const int col = d * 16 + l15;
                vals[(((size_t)b * S_ + qg) * H_ + h) * DH_ + col] =
                    __float2bfloat16(o[mi][d][r] * inv);
            }
        }
}

// ---------------------------------------------------------------------------
extern "C" void kernel_launch(void* const* d_in, const int* in_sizes, int n_in,
                              void* d_out, int out_size, void* d_ws, size_t ws_size,
                              hipStream_t stream)
{
    const float* x    = (const float*)d_in[0];
    const float* cos_ = (const float*)d_in[1];
    const float* sin_ = (const float*)d_in[2];
    const float* Wq   = (const float*)d_in[3];
    const float* Wk   = (const float*)d_in[4];
    const float* Wv   = (const float*)d_in[5];
    const float* Wo   = (const float*)d_in[6];
    float* out = (float*)d_out;

    const size_t NELEM = (size_t)B_ * S_ * D_;       // 8388608
    const size_t WELEM = (size_t)D_ * D_;            // 4194304

    __hip_bfloat16* xb = (__hip_bfloat16*)d_out;     // scratch in d_out
    __hip_bfloat16* wb = xb + NELEM;
    __hip_bfloat16* q    = (__hip_bfloat16*)d_ws;
    __hip_bfloat16* k    = q + NELEM;
    __hip_bfloat16* vt   = k + NELEM;
    __hip_bfloat16* vals = vt + NELEM;
    __hip_bfloat16* wob  = q;                        // reuse q after attention

    const int M = B_ * S_, N = D_, K = D_;
    dim3 gg(N / 128, M / 128), bb(256);
    const int xcb = (int)(NELEM / (256 * 8));
    const int wcb = (int)(WELEM / (256 * 8));

    f2b_kernel<<<xcb, 256, 0, stream>>>(x, xb);
    f2b_kernel<<<wcb, 256, 0, stream>>>(Wq, wb);
    gemm_mfma<1, __hip_bfloat16><<<gg, bb, 0, stream>>>(xb, wb, q, M, N, K);
    f2b_kernel<<<wcb, 256, 0, stream>>>(Wk, wb);
    gemm_mfma<1, __hip_bfloat16><<<gg, bb, 0, stream>>>(xb, wb, k, M, N, K);
    f2b_kernel<<<wcb, 256, 0, stream>>>(Wv, wb);
    gemm_mfma<2, __hip_bfloat16><<<gg, bb, 0, stream>>>(xb, wb, vt, M, N, K);

    const int rope_threads = B_ * H_ * S_ * 64;
    rope_kernel<<<rope_threads / 256, 256, 0, stream>>>(q, cos_, sin_);
    rope_kernel<<<rope_threads / 256, 256, 0, stream>>>(k, cos_, sin_);

    attn_mfma<<<dim3(S_ / 128, B_ * H_), 256, 0, stream>>>(q, k, vt, vals);

    f2b_kernel<<<wcb, 256, 0, stream>>>(Wo, wob);
    gemm_mfma<0, float><<<gg, bb, 0, stream>>>(vals, wob, out, M, N, K);
}

// Round 6
// 612.238 us; speedup vs baseline: 11.4780x; 1.0012x over previous
//
#include <hip/hip_runtime.h>
#include <hip/hip_bf16.h>

#define B_  2
#define S_  2048
#define D_  2048
#define H_  16
#define DH_ 128

typedef __attribute__((ext_vector_type(8))) short bf16x8;
typedef __attribute__((ext_vector_type(4))) float f32x4;

__device__ inline short bf16bits(float v) {
    __hip_bfloat16 h = __float2bfloat16(v);
    return *reinterpret_cast<short*>(&h);
}

// ---------------------------------------------------------------------------
// fp32 -> bf16 cast, 8 elements/thread, vectorized.
// ---------------------------------------------------------------------------
__global__ __launch_bounds__(256)
void f2b_kernel(const float* __restrict__ in, __hip_bfloat16* __restrict__ out)
{
    const size_t i = ((size_t)blockIdx.x * 256 + threadIdx.x) * 8;
    float4 a = *(const float4*)(in + i);
    float4 b = *(const float4*)(in + i + 4);
    short s[8] = { bf16bits(a.x), bf16bits(a.y), bf16bits(a.z), bf16bits(a.w),
                   bf16bits(b.x), bf16bits(b.y), bf16bits(b.z), bf16bits(b.w) };
    *(uint4*)(out + i) = *(const uint4*)s;
}

// ---------------------------------------------------------------------------
// MFMA NT GEMM (m97 structure): C[M,N] = A[M,K] * W[N,K]^T, bf16 in, fp32 acc.
// ---------------------------------------------------------------------------
#define BKg 32

__device__ inline void async16(const __hip_bfloat16* g, short* l) {
    __builtin_amdgcn_global_load_lds(
        (const __attribute__((address_space(1))) void*)g,
        (__attribute__((address_space(3))) void*)l, 16, 0, 0);
}

template<int MODE, typename TO>
__global__ __launch_bounds__(256)
void gemm_mfma(const __hip_bfloat16* __restrict__ A,
               const __hip_bfloat16* __restrict__ W,
               TO* __restrict__ out, int M, int N, int K)
{
    __shared__ __align__(16) short sA[128 * BKg];
    __shared__ __align__(16) short sB[128 * BKg];

    const int tid  = threadIdx.x;
    const int w    = tid >> 6;
    const int lane = tid & 63;
    const int l15  = lane & 15;
    const int quad = lane >> 4;

    const int m0 = blockIdx.y * 128;
    const int n0 = blockIdx.x * 128;

    const int sr0 = w * 32 + (lane >> 2);
    const int scol = (lane & 3) * 8;

    const int wm = (w >> 1) * 64;
    const int wn = (w & 1) * 64;

    f32x4 acc[4][4];
    #pragma unroll
    for (int i = 0; i < 4; i++)
        #pragma unroll
        for (int j = 0; j < 4; j++) acc[i][j] = (f32x4)(0.0f);

    for (int k0 = 0; k0 < K; k0 += BKg) {
        #pragma unroll
        for (int t = 0; t < 2; t++) {
            const int r = sr0 + t * 16;
            async16(A + (size_t)(m0 + r) * K + k0 + scol, sA + (w * 2 + t) * 512);
            async16(W + (size_t)(n0 + r) * K + k0 + scol, sB + (w * 2 + t) * 512);
        }
        __syncthreads();

        bf16x8 af[4], bf[4];
        #pragma unroll
        for (int i = 0; i < 4; i++)
            af[i] = *(const bf16x8*)(sA + (wm + i * 16 + l15) * BKg + quad * 8);
        #pragma unroll
        for (int j = 0; j < 4; j++)
            bf[j] = *(const bf16x8*)(sB + (wn + j * 16 + l15) * BKg + quad * 8);
        #pragma unroll
        for (int i = 0; i < 4; i++)
            #pragma unroll
            for (int j = 0; j < 4; j++)
                acc[i][j] = __builtin_amdgcn_mfma_f32_16x16x32_bf16(af[i], bf[j], acc[i][j], 0, 0, 0);
        __syncthreads();
    }

    #pragma unroll
    for (int i = 0; i < 4; i++) {
        #pragma unroll
        for (int r = 0; r < 4; r++) {
            const int m = m0 + wm + i * 16 + quad * 4 + r;
            #pragma unroll
            for (int j = 0; j < 4; j++) {
                const int n = n0 + wn + j * 16 + l15;
                size_t idx;
                if (MODE == 0) {
                    idx = (size_t)m * N + n;
                } else if (MODE == 1) {
                    const int b  = m / S_, s  = m % S_;
                    const int h  = n / DH_, dh = n % DH_;
                    idx = (((size_t)(b * H_ + h)) * S_ + s) * DH_ + dh;
                } else {
                    const int b  = m / S_, s  = m % S_;
                    const int h  = n / DH_, dh = n % DH_;
                    idx = (((size_t)(b * H_ + h)) * DH_ + dh) * S_ + s;
                }
                if (MODE == 0) ((float*)out)[idx] = acc[i][j][r];
                else ((__hip_bfloat16*)out)[idx] = __float2bfloat16(acc[i][j][r]);
            }
        }
    }
}

// ---------------------------------------------------------------------------
// RoPE in-place on bf16 [B*H*S, DH] rows; cos/sin are fp32 [S, DH].
// ---------------------------------------------------------------------------
__global__ __launch_bounds__(256)
void rope_kernel(__hip_bfloat16* __restrict__ q,
                 const float* __restrict__ cos_,
                 const float* __restrict__ sin_)
{
    const size_t i = (size_t)blockIdx.x * blockDim.x + threadIdx.x;
    const int dh = (int)(i & 63);
    const size_t row = i >> 6;
    const int s = (int)(row % S_);
    __hip_bfloat16* p = q + row * DH_;

    const float x1 = __bfloat162float(p[dh]);
    const float x2 = __bfloat162float(p[dh + 64]);
    const float c1 = cos_[s * DH_ + dh];
    const float s1 = sin_[s * DH_ + dh];
    const float c2 = cos_[s * DH_ + dh + 64];
    const float s2 = sin_[s * DH_ + dh + 64];

    p[dh]      = __float2bfloat16(x1 * c1 - x2 * s1);
    p[dh + 64] = __float2bfloat16(x2 * c2 + x1 * s2);
}

// ---------------------------------------------------------------------------
// Flash attention v2.1: Q-tile 128 (32 rows/wave), kv-tile 64, register-
// prefetch double buffering, deferred l-reduction.
// __launch_bounds__(256, 2): 256-VGPR cap -> ~210 live regs fit, NO SPILL
// (r5 at default cap 128 spilled ~1.2 KB/thread -> 160 MB scratch traffic).
// q,k: [BH,S,DH]; vt: [BH,DH,S]; vals: [B,S,H,DH].
// ---------------------------------------------------------------------------
#define KSTR 136
#define VSTR 72
#define PSTR 72

__global__ __launch_bounds__(256, 2)
void attn_mfma(const __hip_bfloat16* __restrict__ q,
               const __hip_bfloat16* __restrict__ k,
               const __hip_bfloat16* __restrict__ vt,
               __hip_bfloat16* __restrict__ vals)
{
    __shared__ __align__(16) short sK[64 * KSTR];      // 17.0 KB
    __shared__ __align__(16) short sV[128 * VSTR];     // 18.4 KB
    __shared__ __align__(16) short sP[4 * 32 * PSTR];  // 18.4 KB

    const int bh    = blockIdx.y;
    const int qtile = (int)(gridDim.x - 1) - (int)blockIdx.x;  // big first
    const int q0    = qtile * 128;
    const int tid   = threadIdx.x;
    const int w     = tid >> 6;
    const int lane  = tid & 63;
    const int l15   = lane & 15;
    const int quad  = lane >> 4;
    const int qb    = q0 + w * 32;          // wave's 32 q rows

    // ---- Q fragments (A-layout), 2 m-tiles ------------------------------
    bf16x8 qf[2][4];
    #pragma unroll
    for (int mi = 0; mi < 2; mi++) {
        const __hip_bfloat16* qrow =
            q + ((size_t)bh * S_ + qb + mi * 16 + l15) * DH_ + quad * 8;
        #pragma unroll
        for (int c = 0; c < 4; c++)
            qf[mi][c] = *(const bf16x8*)(qrow + c * 32);
    }

    f32x4 o[2][8];
    #pragma unroll
    for (int mi = 0; mi < 2; mi++)
        #pragma unroll
        for (int d = 0; d < 8; d++) o[mi][d] = (f32x4)(0.0f);
    float mrow[2][4], lrow[2][4];
    #pragma unroll
    for (int mi = 0; mi < 2; mi++)
        #pragma unroll
        for (int r = 0; r < 4; r++) { mrow[mi][r] = -1e30f; lrow[mi][r] = 0.f; }

    const float scale = 0.08838834764831845f;   // 1/sqrt(128)

    // staging assignment
    const int kr = tid >> 2, kc = (tid & 3) * 32;
    const int vr = tid >> 1, vc = (tid & 1) * 32;
    const int niter = qtile * 2 + 2;

    uint4 kreg[4], vreg[4];
    {
        const __hip_bfloat16* kg = k + ((size_t)bh * S_ + kr) * DH_ + kc;
        const __hip_bfloat16* vg = vt + ((size_t)bh * DH_ + vr) * S_ + vc;
        #pragma unroll
        for (int u = 0; u < 4; u++) kreg[u] = *(const uint4*)(kg + u * 8);
        #pragma unroll
        for (int u = 0; u < 4; u++) vreg[u] = *(const uint4*)(vg + u * 8);
    }

    for (int it = 0; it < niter; ++it) {
        const int kv0 = it * 64;

        // ---- staged regs -> LDS ------------------------------------------
        {
            short* dk = &sK[kr * KSTR + kc];
            #pragma unroll
            for (int u = 0; u < 4; u++) *(uint4*)(dk + u * 8) = kreg[u];
            short* dv = &sV[vr * VSTR + vc];
            #pragma unroll
            for (int u = 0; u < 4; u++) *(uint4*)(dv + u * 8) = vreg[u];
        }
        __syncthreads();

        // ---- prefetch next tile into regs (overlaps compute) -------------
        if (it + 1 < niter) {
            const int nv = kv0 + 64;
            const __hip_bfloat16* kg = k + ((size_t)bh * S_ + nv + kr) * DH_ + kc;
            const __hip_bfloat16* vg = vt + ((size_t)bh * DH_ + vr) * S_ + nv + vc;
            #pragma unroll
            for (int u = 0; u < 4; u++) kreg[u] = *(const uint4*)(kg + u * 8);
            #pragma unroll
            for (int u = 0; u < 4; u++) vreg[u] = *(const uint4*)(vg + u * 8);
        }

        if (kv0 <= qb + 31) {     // wave has unmasked work in this tile
            // ---- S = Q K^T (K-fragment reused across both m-tiles) -------
            f32x4 s[2][4];
            #pragma unroll
            for (int mi = 0; mi < 2; mi++)
                #pragma unroll
                for (int n = 0; n < 4; n++) s[mi][n] = (f32x4)(0.0f);
            #pragma unroll
            for (int n = 0; n < 4; n++) {
                const short* kp = &sK[(n * 16 + l15) * KSTR + quad * 8];
                #pragma unroll
                for (int c = 0; c < 4; c++) {
                    bf16x8 kf = *(const bf16x8*)(kp + c * 32);
                    s[0][n] = __builtin_amdgcn_mfma_f32_16x16x32_bf16(qf[0][c], kf, s[0][n], 0, 0, 0);
                    s[1][n] = __builtin_amdgcn_mfma_f32_16x16x32_bf16(qf[1][c], kf, s[1][n], 0, 0, 0);
                }
            }

            #pragma unroll
            for (int mi = 0; mi < 2; mi++) {
                const int qbm = qb + mi * 16;
                const bool msk = (kv0 + 63 > qbm);
                float sv[4][4];
                #pragma unroll
                for (int n = 0; n < 4; n++)
                    #pragma unroll
                    for (int r = 0; r < 4; r++) {
                        float x = s[mi][n][r] * scale;
                        if (msk) {
                            const int kvg = kv0 + n * 16 + l15;
                            const int qg  = qbm + quad * 4 + r;
                            if (kvg > qg) x = -1e30f;
                        }
                        sv[n][r] = x;
                    }

                // row max over 16 lanes
                float alpha[4];
                #pragma unroll
                for (int r = 0; r < 4; r++) {
                    float v = fmaxf(fmaxf(sv[0][r], sv[1][r]), fmaxf(sv[2][r], sv[3][r]));
                    #pragma unroll
                    for (int m2 = 8; m2; m2 >>= 1)
                        v = fmaxf(v, __shfl_xor(v, m2, 64));
                    const float mn = fmaxf(mrow[mi][r], v);
                    alpha[r] = __expf(mrow[mi][r] - mn);
                    mrow[mi][r] = mn;
                }
                // exp + per-lane partial l (reduced once in epilogue)
                #pragma unroll
                for (int r = 0; r < 4; r++) {
                    float rs = 0.f;
                    #pragma unroll
                    for (int n = 0; n < 4; n++) {
                        const float p = __expf(sv[n][r] - mrow[mi][r]);
                        sv[n][r] = p;
                        rs += p;
                    }
                    lrow[mi][r] = lrow[mi][r] * alpha[r] + rs;
                }
                #pragma unroll
                for (int d = 0; d < 8; d++)
                    #pragma unroll
                    for (int r = 0; r < 4; r++)
                        o[mi][d][r] *= alpha[r];

                // P: C-layout -> LDS (wave-private)
                short* pb = &sP[(w * 32 + mi * 16) * PSTR];
                #pragma unroll
                for (int n = 0; n < 4; n++)
                    #pragma unroll
                    for (int r = 0; r < 4; r++)
                        pb[(quad * 4 + r) * PSTR + n * 16 + l15] = bf16bits(sv[n][r]);
            }

            // ---- O += P V (V-fragment reused across both m-tiles) --------
            #pragma unroll
            for (int c = 0; c < 2; c++) {
                bf16x8 pf0 = *(const bf16x8*)(&sP[(w * 32 + l15) * PSTR + c * 32 + quad * 8]);
                bf16x8 pf1 = *(const bf16x8*)(&sP[(w * 32 + 16 + l15) * PSTR + c * 32 + quad * 8]);
                #pragma unroll
                for (int d = 0; d < 8; d++) {
                    bf16x8 vf = *(const bf16x8*)(&sV[(d * 16 + l15) * VSTR + c * 32 + quad * 8]);
                    o[0][d] = __builtin_amdgcn_mfma_f32_16x16x32_bf16(pf0, vf, o[0][d], 0, 0, 0);
                    o[1][d] = __builtin_amdgcn_mfma_f32_16x16x32_bf16(pf1, vf, o[1][d], 0, 0, 0);
                }
            }
        }
        __syncthreads();
    }

    // ---- epilogue: reduce l across lanes, normalize, store ---------------
    const int b = bh >> 4, h = bh & 15;
    #pragma unroll
    for (int mi = 0; mi < 2; mi++)
        #pragma unroll
        for (int r = 0; r < 4; r++) {
            float l = lrow[mi][r];
            #pragma unroll
            for (int m2 = 8; m2; m2 >>= 1)
                l += __shfl_xor(l, m2, 64);
            const float inv = 1.0f / l;
            const int qg = qb + mi * 16 + quad * 4 + r;
            #pragma unroll
            for (int d = 0; d < 8; d++) {
                const int col = d * 16 + l15;
                vals[(((size_t)b * S_ + qg) * H_ + h) * DH_ + col] =
                    __float2bfloat16(o[mi][d][r] * inv);
            }
        }
}

// ---------------------------------------------------------------------------
extern "C" void kernel_launch(void* const* d_in, const int* in_sizes, int n_in,
                              void* d_out, int out_size, void* d_ws, size_t ws_size,
                              hipStream_t stream)
{
    const float* x    = (const float*)d_in[0];
    const float* cos_ = (const float*)d_in[1];
    const float* sin_ = (const float*)d_in[2];
    const float* Wq   = (const float*)d_in[3];
    const float* Wk   = (const float*)d_in[4];
    const float* Wv   = (const float*)d_in[5];
    const float* Wo   = (const float*)d_in[6];
    float* out = (float*)d_out;

    const size_t NELEM = (size_t)B_ * S_ * D_;       // 8388608
    const size_t WELEM = (size_t)D_ * D_;            // 4194304

    __hip_bfloat16* xb = (__hip_bfloat16*)d_out;     // scratch in d_out
    __hip_bfloat16* wb = xb + NELEM;
    __hip_bfloat16* q    = (__hip_bfloat16*)d_ws;
    __hip_bfloat16* k    = q + NELEM;
    __hip_bfloat16* vt   = k + NELEM;
    __hip_bfloat16* vals = vt + NELEM;
    __hip_bfloat16* wob  = q;                        // reuse q after attention

    const int M = B_ * S_, N = D_, K = D_;
    dim3 gg(N / 128, M / 128), bb(256);
    const int xcb = (int)(NELEM / (256 * 8));
    const int wcb = (int)(WELEM / (256 * 8));

    f2b_kernel<<<xcb, 256, 0, stream>>>(x, xb);
    f2b_kernel<<<wcb, 256, 0, stream>>>(Wq, wb);
    gemm_mfma<1, __hip_bfloat16><<<gg, bb, 0, stream>>>(xb, wb, q, M, N, K);
    f2b_kernel<<<wcb, 256, 0, stream>>>(Wk, wb);
    gemm_mfma<1, __hip_bfloat16><<<gg, bb, 0, stream>>>(xb, wb, k, M, N, K);
    f2b_kernel<<<wcb, 256, 0, stream>>>(Wv, wb);
    gemm_mfma<2, __hip_bfloat16><<<gg, bb, 0, stream>>>(xb, wb, vt, M, N, K);

    const int rope_threads = B_ * H_ * S_ * 64;
    rope_kernel<<<rope_threads / 256, 256, 0, stream>>>(q, cos_, sin_);
    rope_kernel<<<rope_threads / 256, 256, 0, stream>>>(k, cos_, sin_);

    attn_mfma<<<dim3(S_ / 128, B_ * H_), 256, 0, stream>>>(q, k, vt, vals);

    f2b_kernel<<<wcb, 256, 0, stream>>>(Wo, wob);
    gemm_mfma<0, float><<<gg, bb, 0, stream>>>(vals, wob, out, M, N, K);
}

// Round 7
// 574.433 us; speedup vs baseline: 12.2334x; 1.0658x over previous
//
#include <hip/hip_runtime.h>
#include <hip/hip_bf16.h>

#define B_  2
#define S_  2048
#define D_  2048
#define H_  16
#define DH_ 128

typedef __attribute__((ext_vector_type(8))) short bf16x8;
typedef __attribute__((ext_vector_type(4))) float f32x4;

__device__ inline short bf16bits(float v) {
    __hip_bfloat16 h = __float2bfloat16(v);
    return *reinterpret_cast<short*>(&h);
}

// ---------------------------------------------------------------------------
// fp32 -> bf16 cast, 8 elements/thread, vectorized.
// ---------------------------------------------------------------------------
__global__ __launch_bounds__(256)
void f2b_kernel(const float* __restrict__ in, __hip_bfloat16* __restrict__ out)
{
    const size_t i = ((size_t)blockIdx.x * 256 + threadIdx.x) * 8;
    float4 a = *(const float4*)(in + i);
    float4 b = *(const float4*)(in + i + 4);
    short s[8] = { bf16bits(a.x), bf16bits(a.y), bf16bits(a.z), bf16bits(a.w),
                   bf16bits(b.x), bf16bits(b.y), bf16bits(b.z), bf16bits(b.w) };
    *(uint4*)(out + i) = *(const uint4*)s;
}

// ---------------------------------------------------------------------------
// MFMA NT GEMM (m97 structure): C[M,N] = A[M,K] * W[N,K]^T, bf16 in, fp32 acc.
// ---------------------------------------------------------------------------
#define BKg 32

__device__ inline void async16(const __hip_bfloat16* g, short* l) {
    __builtin_amdgcn_global_load_lds(
        (const __attribute__((address_space(1))) void*)g,
        (__attribute__((address_space(3))) void*)l, 16, 0, 0);
}

template<int MODE, typename TO>
__global__ __launch_bounds__(256)
void gemm_mfma(const __hip_bfloat16* __restrict__ A,
               const __hip_bfloat16* __restrict__ W,
               TO* __restrict__ out, int M, int N, int K)
{
    __shared__ __align__(16) short sA[128 * BKg];
    __shared__ __align__(16) short sB[128 * BKg];

    const int tid  = threadIdx.x;
    const int w    = tid >> 6;
    const int lane = tid & 63;
    const int l15  = lane & 15;
    const int quad = lane >> 4;

    const int m0 = blockIdx.y * 128;
    const int n0 = blockIdx.x * 128;

    const int sr0 = w * 32 + (lane >> 2);
    const int scol = (lane & 3) * 8;

    const int wm = (w >> 1) * 64;
    const int wn = (w & 1) * 64;

    f32x4 acc[4][4];
    #pragma unroll
    for (int i = 0; i < 4; i++)
        #pragma unroll
        for (int j = 0; j < 4; j++) acc[i][j] = (f32x4)(0.0f);

    for (int k0 = 0; k0 < K; k0 += BKg) {
        #pragma unroll
        for (int t = 0; t < 2; t++) {
            const int r = sr0 + t * 16;
            async16(A + (size_t)(m0 + r) * K + k0 + scol, sA + (w * 2 + t) * 512);
            async16(W + (size_t)(n0 + r) * K + k0 + scol, sB + (w * 2 + t) * 512);
        }
        __syncthreads();

        bf16x8 af[4], bf[4];
        #pragma unroll
        for (int i = 0; i < 4; i++)
            af[i] = *(const bf16x8*)(sA + (wm + i * 16 + l15) * BKg + quad * 8);
        #pragma unroll
        for (int j = 0; j < 4; j++)
            bf[j] = *(const bf16x8*)(sB + (wn + j * 16 + l15) * BKg + quad * 8);
        #pragma unroll
        for (int i = 0; i < 4; i++)
            #pragma unroll
            for (int j = 0; j < 4; j++)
                acc[i][j] = __builtin_amdgcn_mfma_f32_16x16x32_bf16(af[i], bf[j], acc[i][j], 0, 0, 0);
        __syncthreads();
    }

    #pragma unroll
    for (int i = 0; i < 4; i++) {
        #pragma unroll
        for (int r = 0; r < 4; r++) {
            const int m = m0 + wm + i * 16 + quad * 4 + r;
            #pragma unroll
            for (int j = 0; j < 4; j++) {
                const int n = n0 + wn + j * 16 + l15;
                size_t idx;
                if (MODE == 0) {
                    idx = (size_t)m * N + n;
                } else if (MODE == 1) {
                    const int b  = m / S_, s  = m % S_;
                    const int h  = n / DH_, dh = n % DH_;
                    idx = (((size_t)(b * H_ + h)) * S_ + s) * DH_ + dh;
                } else {
                    const int b  = m / S_, s  = m % S_;
                    const int h  = n / DH_, dh = n % DH_;
                    idx = (((size_t)(b * H_ + h)) * DH_ + dh) * S_ + s;
                }
                if (MODE == 0) ((float*)out)[idx] = acc[i][j][r];
                else ((__hip_bfloat16*)out)[idx] = __float2bfloat16(acc[i][j][r]);
            }
        }
    }
}

// ---------------------------------------------------------------------------
// RoPE in-place on bf16 [B*H*S, DH] rows; cos/sin are fp32 [S, DH].
// ---------------------------------------------------------------------------
__global__ __launch_bounds__(256)
void rope_kernel(__hip_bfloat16* __restrict__ q,
                 const float* __restrict__ cos_,
                 const float* __restrict__ sin_)
{
    const size_t i = (size_t)blockIdx.x * blockDim.x + threadIdx.x;
    const int dh = (int)(i & 63);
    const size_t row = i >> 6;
    const int s = (int)(row % S_);
    __hip_bfloat16* p = q + row * DH_;

    const float x1 = __bfloat162float(p[dh]);
    const float x2 = __bfloat162float(p[dh + 64]);
    const float c1 = cos_[s * DH_ + dh];
    const float s1 = sin_[s * DH_ + dh];
    const float c2 = cos_[s * DH_ + dh + 64];
    const float s2 = sin_[s * DH_ + dh + 64];

    p[dh]      = __float2bfloat16(x1 * c1 - x2 * s1);
    p[dh + 64] = __float2bfloat16(x2 * c2 + x1 * s2);
}

// ---------------------------------------------------------------------------
// Flash attention v2.2: Q-tile 128 (32 rows/wave), kv-tile 64, register-
// prefetch double buffering, deferred l-reduction.
// amdgpu_waves_per_eu(2,2): pins allocator target to 2 waves/EU -> 256-VGPR
// budget. (r5/r6: launch_bounds(256,2) sets only the MIN -> scheduler still
// targeted 4 waves/EU, capped 128 VGPRs, spilled ~170 MB scratch traffic.)
// Occupancy is LDS-pinned at 2 blocks/CU (54 KB) anyway, so (2,2) is free.
// q,k: [BH,S,DH]; vt: [BH,DH,S]; vals: [B,S,H,DH].
// ---------------------------------------------------------------------------
#define KSTR 136
#define VSTR 72
#define PSTR 72

__global__ __launch_bounds__(256) __attribute__((amdgpu_waves_per_eu(2, 2)))
void attn_mfma(const __hip_bfloat16* __restrict__ q,
               const __hip_bfloat16* __restrict__ k,
               const __hip_bfloat16* __restrict__ vt,
               __hip_bfloat16* __restrict__ vals)
{
    __shared__ __align__(16) short sK[64 * KSTR];      // 17.0 KB
    __shared__ __align__(16) short sV[128 * VSTR];     // 18.4 KB
    __shared__ __align__(16) short sP[4 * 32 * PSTR];  // 18.4 KB

    const int bh    = blockIdx.y;
    const int qtile = (int)(gridDim.x - 1) - (int)blockIdx.x;  // big first
    const int q0    = qtile * 128;
    const int tid   = threadIdx.x;
    const int w     = tid >> 6;
    const int lane  = tid & 63;
    const int l15   = lane & 15;
    const int quad  = lane >> 4;
    const int qb    = q0 + w * 32;          // wave's 32 q rows

    // ---- Q fragments (A-layout), 2 m-tiles ------------------------------
    bf16x8 qf[2][4];
    #pragma unroll
    for (int mi = 0; mi < 2; mi++) {
        const __hip_bfloat16* qrow =
            q + ((size_t)bh * S_ + qb + mi * 16 + l15) * DH_ + quad * 8;
        #pragma unroll
        for (int c = 0; c < 4; c++)
            qf[mi][c] = *(const bf16x8*)(qrow + c * 32);
    }

    f32x4 o[2][8];
    #pragma unroll
    for (int mi = 0; mi < 2; mi++)
        #pragma unroll
        for (int d = 0; d < 8; d++) o[mi][d] = (f32x4)(0.0f);
    float mrow[2][4], lrow[2][4];
    #pragma unroll
    for (int mi = 0; mi < 2; mi++)
        #pragma unroll
        for (int r = 0; r < 4; r++) { mrow[mi][r] = -1e30f; lrow[mi][r] = 0.f; }

    const float scale = 0.08838834764831845f;   // 1/sqrt(128)

    // staging assignment
    const int kr = tid >> 2, kc = (tid & 3) * 32;
    const int vr = tid >> 1, vc = (tid & 1) * 32;
    const int niter = qtile * 2 + 2;

    uint4 kreg[4], vreg[4];
    {
        const __hip_bfloat16* kg = k + ((size_t)bh * S_ + kr) * DH_ + kc;
        const __hip_bfloat16* vg = vt + ((size_t)bh * DH_ + vr) * S_ + vc;
        #pragma unroll
        for (int u = 0; u < 4; u++) kreg[u] = *(const uint4*)(kg + u * 8);
        #pragma unroll
        for (int u = 0; u < 4; u++) vreg[u] = *(const uint4*)(vg + u * 8);
    }

    for (int it = 0; it < niter; ++it) {
        const int kv0 = it * 64;

        // ---- staged regs -> LDS ------------------------------------------
        {
            short* dk = &sK[kr * KSTR + kc];
            #pragma unroll
            for (int u = 0; u < 4; u++) *(uint4*)(dk + u * 8) = kreg[u];
            short* dv = &sV[vr * VSTR + vc];
            #pragma unroll
            for (int u = 0; u < 4; u++) *(uint4*)(dv + u * 8) = vreg[u];
        }
        __syncthreads();

        // ---- prefetch next tile into regs (overlaps compute) -------------
        if (it + 1 < niter) {
            const int nv = kv0 + 64;
            const __hip_bfloat16* kg = k + ((size_t)bh * S_ + nv + kr) * DH_ + kc;
            const __hip_bfloat16* vg = vt + ((size_t)bh * DH_ + vr) * S_ + nv + vc;
            #pragma unroll
            for (int u = 0; u < 4; u++) kreg[u] = *(const uint4*)(kg + u * 8);
            #pragma unroll
            for (int u = 0; u < 4; u++) vreg[u] = *(const uint4*)(vg + u * 8);
        }

        if (kv0 <= qb + 31) {     // wave has unmasked work in this tile
            // ---- S = Q K^T (K-fragment reused across both m-tiles) -------
            f32x4 s[2][4];
            #pragma unroll
            for (int mi = 0; mi < 2; mi++)
                #pragma unroll
                for (int n = 0; n < 4; n++) s[mi][n] = (f32x4)(0.0f);
            #pragma unroll
            for (int n = 0; n < 4; n++) {
                const short* kp = &sK[(n * 16 + l15) * KSTR + quad * 8];
                #pragma unroll
                for (int c = 0; c < 4; c++) {
                    bf16x8 kf = *(const bf16x8*)(kp + c * 32);
                    s[0][n] = __builtin_amdgcn_mfma_f32_16x16x32_bf16(qf[0][c], kf, s[0][n], 0, 0, 0);
                    s[1][n] = __builtin_amdgcn_mfma_f32_16x16x32_bf16(qf[1][c], kf, s[1][n], 0, 0, 0);
                }
            }

            #pragma unroll
            for (int mi = 0; mi < 2; mi++) {
                const int qbm = qb + mi * 16;
                const bool msk = (kv0 + 63 > qbm);
                float sv[4][4];
                #pragma unroll
                for (int n = 0; n < 4; n++)
                    #pragma unroll
                    for (int r = 0; r < 4; r++) {
                        float x = s[mi][n][r] * scale;
                        if (msk) {
                            const int kvg = kv0 + n * 16 + l15;
                            const int qg  = qbm + quad * 4 + r;
                            if (kvg > qg) x = -1e30f;
                        }
                        sv[n][r] = x;
                    }

                // row max over 16 lanes
                float alpha[4];
                #pragma unroll
                for (int r = 0; r < 4; r++) {
                    float v = fmaxf(fmaxf(sv[0][r], sv[1][r]), fmaxf(sv[2][r], sv[3][r]));
                    #pragma unroll
                    for (int m2 = 8; m2; m2 >>= 1)
                        v = fmaxf(v, __shfl_xor(v, m2, 64));
                    const float mn = fmaxf(mrow[mi][r], v);
                    alpha[r] = __expf(mrow[mi][r] - mn);
                    mrow[mi][r] = mn;
                }
                // exp + per-lane partial l (reduced once in epilogue)
                #pragma unroll
                for (int r = 0; r < 4; r++) {
                    float rs = 0.f;
                    #pragma unroll
                    for (int n = 0; n < 4; n++) {
                        const float p = __expf(sv[n][r] - mrow[mi][r]);
                        sv[n][r] = p;
                        rs += p;
                    }
                    lrow[mi][r] = lrow[mi][r] * alpha[r] + rs;
                }
                #pragma unroll
                for (int d = 0; d < 8; d++)
                    #pragma unroll
                    for (int r = 0; r < 4; r++)
                        o[mi][d][r] *= alpha[r];

                // P: C-layout -> LDS (wave-private)
                short* pb = &sP[(w * 32 + mi * 16) * PSTR];
                #pragma unroll
                for (int n = 0; n < 4; n++)
                    #pragma unroll
                    for (int r = 0; r < 4; r++)
                        pb[(quad * 4 + r) * PSTR + n * 16 + l15] = bf16bits(sv[n][r]);
            }

            // ---- O += P V (V-fragment reused across both m-tiles) --------
            #pragma unroll
            for (int c = 0; c < 2; c++) {
                bf16x8 pf0 = *(const bf16x8*)(&sP[(w * 32 + l15) * PSTR + c * 32 + quad * 8]);
                bf16x8 pf1 = *(const bf16x8*)(&sP[(w * 32 + 16 + l15) * PSTR + c * 32 + quad * 8]);
                #pragma unroll
                for (int d = 0; d < 8; d++) {
                    bf16x8 vf = *(const bf16x8*)(&sV[(d * 16 + l15) * VSTR + c * 32 + quad * 8]);
                    o[0][d] = __builtin_amdgcn_mfma_f32_16x16x32_bf16(pf0, vf, o[0][d], 0, 0, 0);
                    o[1][d] = __builtin_amdgcn_mfma_f32_16x16x32_bf16(pf1, vf, o[1][d], 0, 0, 0);
                }
            }
        }
        __syncthreads();
    }

    // ---- epilogue: reduce l across lanes, normalize, store ---------------
    const int b = bh >> 4, h = bh & 15;
    #pragma unroll
    for (int mi = 0; mi < 2; mi++)
        #pragma unroll
        for (int r = 0; r < 4; r++) {
            float l = lrow[mi][r];
            #pragma unroll
            for (int m2 = 8; m2; m2 >>= 1)
                l += __shfl_xor(l, m2, 64);
            const float inv = 1.0f / l;
            const int qg = qb + mi * 16 + quad * 4 + r;
            #pragma unroll
            for (int d = 0; d < 8; d++) {
                const int col = d * 16 + l15;
                vals[(((size_t)b * S_ + qg) * H_ + h) * DH_ + col] =
                    __float2bfloat16(o[mi][d][r] * inv);
            }
        }
}

// ---------------------------------------------------------------------------
extern "C" void kernel_launch(void* const* d_in, const int* in_sizes, int n_in,
                              void* d_out, int out_size, void* d_ws, size_t ws_size,
                              hipStream_t stream)
{
    const float* x    = (const float*)d_in[0];
    const float* cos_ = (const float*)d_in[1];
    const float* sin_ = (const float*)d_in[2];
    const float* Wq   = (const float*)d_in[3];
    const float* Wk   = (const float*)d_in[4];
    const float* Wv   = (const float*)d_in[5];
    const float* Wo   = (const float*)d_in[6];
    float* out = (float*)d_out;

    const size_t NELEM = (size_t)B_ * S_ * D_;       // 8388608
    const size_t WELEM = (size_t)D_ * D_;            // 4194304

    __hip_bfloat16* xb = (__hip_bfloat16*)d_out;     // scratch in d_out
    __hip_bfloat16* wb = xb + NELEM;
    __hip_bfloat16* q    = (__hip_bfloat16*)d_ws;
    __hip_bfloat16* k    = q + NELEM;
    __hip_bfloat16* vt   = k + NELEM;
    __hip_bfloat16* vals = vt + NELEM;
    __hip_bfloat16* wob  = q;                        // reuse q after attention

    const int M = B_ * S_, N = D_, K = D_;
    dim3 gg(N / 128, M / 128), bb(256);
    const int xcb = (int)(NELEM / (256 * 8));
    const int wcb = (int)(WELEM / (256 * 8));

    f2b_kernel<<<xcb, 256, 0, stream>>>(x, xb);
    f2b_kernel<<<wcb, 256, 0, stream>>>(Wq, wb);
    gemm_mfma<1, __hip_bfloat16><<<gg, bb, 0, stream>>>(xb, wb, q, M, N, K);
    f2b_kernel<<<wcb, 256, 0, stream>>>(Wk, wb);
    gemm_mfma<1, __hip_bfloat16><<<gg, bb, 0, stream>>>(xb, wb, k, M, N, K);
    f2b_kernel<<<wcb, 256, 0, stream>>>(Wv, wb);
    gemm_mfma<2, __hip_bfloat16><<<gg, bb, 0, stream>>>(xb, wb, vt, M, N, K);

    const int rope_threads = B_ * H_ * S_ * 64;
    rope_kernel<<<rope_threads / 256, 256, 0, stream>>>(q, cos_, sin_);
    rope_kernel<<<rope_threads / 256, 256, 0, stream>>>(k, cos_, sin_);

    attn_mfma<<<dim3(S_ / 128, B_ * H_), 256, 0, stream>>>(q, k, vt, vals);

    f2b_kernel<<<wcb, 256, 0, stream>>>(Wo, wob);
    gemm_mfma<0, float><<<gg, bb, 0, stream>>>(vals, wob, out, M, N, K);
}

// Round 8
// 526.175 us; speedup vs baseline: 13.3554x; 1.0917x over previous
//
#include <hip/hip_runtime.h>
#include <hip/hip_bf16.h>

#define B_  2
#define S_  2048
#define D_  2048
#define H_  16
#define DH_ 128

typedef __attribute__((ext_vector_type(8))) short bf16x8;
typedef __attribute__((ext_vector_type(4))) float f32x4;

__device__ inline short bf16bits(float v) {
    __hip_bfloat16 h = __float2bfloat16(v);
    return *reinterpret_cast<short*>(&h);
}

// ---------------------------------------------------------------------------
// fp32 -> bf16 cast, 8 elements/thread.
// ---------------------------------------------------------------------------
__global__ __launch_bounds__(256)
void f2b_kernel(const float* __restrict__ in, __hip_bfloat16* __restrict__ out)
{
    const size_t i = ((size_t)blockIdx.x * 256 + threadIdx.x) * 8;
    float4 a = *(const float4*)(in + i);
    float4 b = *(const float4*)(in + i + 4);
    short s[8] = { bf16bits(a.x), bf16bits(a.y), bf16bits(a.z), bf16bits(a.w),
                   bf16bits(b.x), bf16bits(b.y), bf16bits(b.z), bf16bits(b.w) };
    *(uint4*)(out + i) = *(const uint4*)s;
}

// three weights in one launch (per-block pointer select)
__global__ __launch_bounds__(256)
void f2b3_kernel(const float* __restrict__ i0, const float* __restrict__ i1,
                 const float* __restrict__ i2, __hip_bfloat16* __restrict__ o0,
                 __hip_bfloat16* __restrict__ o1, __hip_bfloat16* __restrict__ o2,
                 int per)
{
    const int sel = blockIdx.x / per, rem = blockIdx.x % per;
    const float* in = sel == 0 ? i0 : (sel == 1 ? i1 : i2);
    __hip_bfloat16* out = sel == 0 ? o0 : (sel == 1 ? o1 : o2);
    const size_t i = ((size_t)rem * 256 + threadIdx.x) * 8;
    float4 a = *(const float4*)(in + i);
    float4 b = *(const float4*)(in + i + 4);
    short s[8] = { bf16bits(a.x), bf16bits(a.y), bf16bits(a.z), bf16bits(a.w),
                   bf16bits(b.x), bf16bits(b.y), bf16bits(b.z), bf16bits(b.w) };
    *(uint4*)(out + i) = *(const uint4*)s;
}

// ---------------------------------------------------------------------------
// m97-structure MFMA GEMM bits shared by gemm_qkv / gemm_mfma.
// ---------------------------------------------------------------------------
#define BKg 32

__device__ inline void async16(const __hip_bfloat16* g, short* l) {
    __builtin_amdgcn_global_load_lds(
        (const __attribute__((address_space(1))) void*)g,
        (__attribute__((address_space(3))) void*)l, 16, 0, 0);
}

// ---------------------------------------------------------------------------
// Merged QKV GEMM: one dispatch, 1536 blocks (3x 512) -> ~6 blocks/CU capacity
// vs 2/CU for the separate GEMMs (the r7 390-TF limiter was overlap, not ALU).
// nsel = blockIdx.x>>4 selects weight + output: 0->q, 1->k, 2->vt(transposed).
// ---------------------------------------------------------------------------
__global__ __launch_bounds__(256)
void gemm_qkv(const __hip_bfloat16* __restrict__ A,
              const __hip_bfloat16* __restrict__ wq,
              const __hip_bfloat16* __restrict__ wk,
              const __hip_bfloat16* __restrict__ wv,
              __hip_bfloat16* __restrict__ q,
              __hip_bfloat16* __restrict__ k,
              __hip_bfloat16* __restrict__ vt)
{
    __shared__ __align__(16) short sA[128 * BKg];
    __shared__ __align__(16) short sB[128 * BKg];

    const int tid  = threadIdx.x;
    const int w    = tid >> 6;
    const int lane = tid & 63;
    const int l15  = lane & 15;
    const int quad = lane >> 4;

    const int nsel = (int)blockIdx.x >> 4;          // 0:q 1:k 2:v
    const int n0   = ((int)blockIdx.x & 15) * 128;  // within [0, 2048)
    const int m0   = (int)blockIdx.y * 128;
    const __hip_bfloat16* W = nsel == 0 ? wq : (nsel == 1 ? wk : wv);

    const int sr0  = w * 32 + (lane >> 2);
    const int scol = (lane & 3) * 8;
    const int wm = (w >> 1) * 64;
    const int wn = (w & 1) * 64;

    f32x4 acc[4][4];
    #pragma unroll
    for (int i = 0; i < 4; i++)
        #pragma unroll
        for (int j = 0; j < 4; j++) acc[i][j] = (f32x4)(0.0f);

    for (int k0 = 0; k0 < D_; k0 += BKg) {
        #pragma unroll
        for (int t = 0; t < 2; t++) {
            const int r = sr0 + t * 16;
            async16(A + (size_t)(m0 + r) * D_ + k0 + scol, sA + (w * 2 + t) * 512);
            async16(W + (size_t)(n0 + r) * D_ + k0 + scol, sB + (w * 2 + t) * 512);
        }
        __syncthreads();

        bf16x8 af[4], bf[4];
        #pragma unroll
        for (int i = 0; i < 4; i++)
            af[i] = *(const bf16x8*)(sA + (wm + i * 16 + l15) * BKg + quad * 8);
        #pragma unroll
        for (int j = 0; j < 4; j++)
            bf[j] = *(const bf16x8*)(sB + (wn + j * 16 + l15) * BKg + quad * 8);
        #pragma unroll
        for (int i = 0; i < 4; i++)
            #pragma unroll
            for (int j = 0; j < 4; j++)
                acc[i][j] = __builtin_amdgcn_mfma_f32_16x16x32_bf16(af[i], bf[j], acc[i][j], 0, 0, 0);
        __syncthreads();
    }

    __hip_bfloat16* out = nsel == 0 ? q : (nsel == 1 ? k : vt);
    #pragma unroll
    for (int i = 0; i < 4; i++) {
        #pragma unroll
        for (int r = 0; r < 4; r++) {
            const int m = m0 + wm + i * 16 + quad * 4 + r;
            const int b = m / S_, s = m % S_;
            #pragma unroll
            for (int j = 0; j < 4; j++) {
                const int n  = n0 + wn + j * 16 + l15;
                const int h  = n / DH_, dh = n % DH_;
                const size_t idx = (nsel == 2)
                    ? (((size_t)(b * H_ + h)) * DH_ + dh) * S_ + s
                    : (((size_t)(b * H_ + h)) * S_ + s) * DH_ + dh;
                out[idx] = __float2bfloat16(acc[i][j][r]);
            }
        }
    }
}

// ---------------------------------------------------------------------------
// Final projection GEMM: C[M,N] = A[M,K] * W[N,K]^T, bf16 in, fp32 out.
// ---------------------------------------------------------------------------
__global__ __launch_bounds__(256)
void gemm_mfma(const __hip_bfloat16* __restrict__ A,
               const __hip_bfloat16* __restrict__ W,
               float* __restrict__ out, int M, int N, int K)
{
    __shared__ __align__(16) short sA[128 * BKg];
    __shared__ __align__(16) short sB[128 * BKg];

    const int tid  = threadIdx.x;
    const int w    = tid >> 6;
    const int lane = tid & 63;
    const int l15  = lane & 15;
    const int quad = lane >> 4;

    const int m0 = blockIdx.y * 128;
    const int n0 = blockIdx.x * 128;

    const int sr0 = w * 32 + (lane >> 2);
    const int scol = (lane & 3) * 8;
    const int wm = (w >> 1) * 64;
    const int wn = (w & 1) * 64;

    f32x4 acc[4][4];
    #pragma unroll
    for (int i = 0; i < 4; i++)
        #pragma unroll
        for (int j = 0; j < 4; j++) acc[i][j] = (f32x4)(0.0f);

    for (int k0 = 0; k0 < K; k0 += BKg) {
        #pragma unroll
        for (int t = 0; t < 2; t++) {
            const int r = sr0 + t * 16;
            async16(A + (size_t)(m0 + r) * K + k0 + scol, sA + (w * 2 + t) * 512);
            async16(W + (size_t)(n0 + r) * K + k0 + scol, sB + (w * 2 + t) * 512);
        }
        __syncthreads();

        bf16x8 af[4], bf[4];
        #pragma unroll
        for (int i = 0; i < 4; i++)
            af[i] = *(const bf16x8*)(sA + (wm + i * 16 + l15) * BKg + quad * 8);
        #pragma unroll
        for (int j = 0; j < 4; j++)
            bf[j] = *(const bf16x8*)(sB + (wn + j * 16 + l15) * BKg + quad * 8);
        #pragma unroll
        for (int i = 0; i < 4; i++)
            #pragma unroll
            for (int j = 0; j < 4; j++)
                acc[i][j] = __builtin_amdgcn_mfma_f32_16x16x32_bf16(af[i], bf[j], acc[i][j], 0, 0, 0);
        __syncthreads();
    }

    #pragma unroll
    for (int i = 0; i < 4; i++) {
        #pragma unroll
        for (int r = 0; r < 4; r++) {
            const int m = m0 + wm + i * 16 + quad * 4 + r;
            #pragma unroll
            for (int j = 0; j < 4; j++) {
                const int n = n0 + wn + j * 16 + l15;
                out[(size_t)m * N + n] = acc[i][j][r];
            }
        }
    }
}

// ---------------------------------------------------------------------------
// RoPE on q AND k in one launch; cos/sin fp32 [S, DH].
// ---------------------------------------------------------------------------
__global__ __launch_bounds__(256)
void rope2_kernel(__hip_bfloat16* __restrict__ q, __hip_bfloat16* __restrict__ k,
                  const float* __restrict__ cos_, const float* __restrict__ sin_,
                  int per)
{
    const int sel = blockIdx.x / per, rem = blockIdx.x % per;
    __hip_bfloat16* base = sel == 0 ? q : k;
    const size_t i = (size_t)rem * blockDim.x + threadIdx.x;
    const int dh = (int)(i & 63);
    const size_t row = i >> 6;
    const int s = (int)(row % S_);
    __hip_bfloat16* p = base + row * DH_;

    const float x1 = __bfloat162float(p[dh]);
    const float x2 = __bfloat162float(p[dh + 64]);
    const float c1 = cos_[s * DH_ + dh];
    const float s1 = sin_[s * DH_ + dh];
    const float c2 = cos_[s * DH_ + dh + 64];
    const float s2 = sin_[s * DH_ + dh + 64];

    p[dh]      = __float2bfloat16(x1 * c1 - x2 * s1);
    p[dh + 64] = __float2bfloat16(x2 * c2 + x1 * s2);
}

// ---------------------------------------------------------------------------
// Flash attention v2.2 (unchanged from r7): Q-tile 128, kv-tile 64,
// register-prefetch double buffering, deferred l-reduction,
// amdgpu_waves_per_eu(2,2).
// ---------------------------------------------------------------------------
#define KSTR 136
#define VSTR 72
#define PSTR 72

__global__ __launch_bounds__(256) __attribute__((amdgpu_waves_per_eu(2, 2)))
void attn_mfma(const __hip_bfloat16* __restrict__ q,
               const __hip_bfloat16* __restrict__ k,
               const __hip_bfloat16* __restrict__ vt,
               __hip_bfloat16* __restrict__ vals)
{
    __shared__ __align__(16) short sK[64 * KSTR];
    __shared__ __align__(16) short sV[128 * VSTR];
    __shared__ __align__(16) short sP[4 * 32 * PSTR];

    const int bh    = blockIdx.y;
    const int qtile = (int)(gridDim.x - 1) - (int)blockIdx.x;
    const int q0    = qtile * 128;
    const int tid   = threadIdx.x;
    const int w     = tid >> 6;
    const int lane  = tid & 63;
    const int l15   = lane & 15;
    const int quad  = lane >> 4;
    const int qb    = q0 + w * 32;

    bf16x8 qf[2][4];
    #pragma unroll
    for (int mi = 0; mi < 2; mi++) {
        const __hip_bfloat16* qrow =
            q + ((size_t)bh * S_ + qb + mi * 16 + l15) * DH_ + quad * 8;
        #pragma unroll
        for (int c = 0; c < 4; c++)
            qf[mi][c] = *(const bf16x8*)(qrow + c * 32);
    }

    f32x4 o[2][8];
    #pragma unroll
    for (int mi = 0; mi < 2; mi++)
        #pragma unroll
        for (int d = 0; d < 8; d++) o[mi][d] = (f32x4)(0.0f);
    float mrow[2][4], lrow[2][4];
    #pragma unroll
    for (int mi = 0; mi < 2; mi++)
        #pragma unroll
        for (int r = 0; r < 4; r++) { mrow[mi][r] = -1e30f; lrow[mi][r] = 0.f; }

    const float scale = 0.08838834764831845f;

    const int kr = tid >> 2, kc = (tid & 3) * 32;
    const int vr = tid >> 1, vc = (tid & 1) * 32;
    const int niter = qtile * 2 + 2;

    uint4 kreg[4], vreg[4];
    {
        const __hip_bfloat16* kg = k + ((size_t)bh * S_ + kr) * DH_ + kc;
        const __hip_bfloat16* vg = vt + ((size_t)bh * DH_ + vr) * S_ + vc;
        #pragma unroll
        for (int u = 0; u < 4; u++) kreg[u] = *(const uint4*)(kg + u * 8);
        #pragma unroll
        for (int u = 0; u < 4; u++) vreg[u] = *(const uint4*)(vg + u * 8);
    }

    for (int it = 0; it < niter; ++it) {
        const int kv0 = it * 64;

        {
            short* dk = &sK[kr * KSTR + kc];
            #pragma unroll
            for (int u = 0; u < 4; u++) *(uint4*)(dk + u * 8) = kreg[u];
            short* dv = &sV[vr * VSTR + vc];
            #pragma unroll
            for (int u = 0; u < 4; u++) *(uint4*)(dv + u * 8) = vreg[u];
        }
        __syncthreads();

        if (it + 1 < niter) {
            const int nv = kv0 + 64;
            const __hip_bfloat16* kg = k + ((size_t)bh * S_ + nv + kr) * DH_ + kc;
            const __hip_bfloat16* vg = vt + ((size_t)bh * DH_ + vr) * S_ + nv + vc;
            #pragma unroll
            for (int u = 0; u < 4; u++) kreg[u] = *(const uint4*)(kg + u * 8);
            #pragma unroll
            for (int u = 0; u < 4; u++) vreg[u] = *(const uint4*)(vg + u * 8);
        }

        if (kv0 <= qb + 31) {
            f32x4 s[2][4];
            #pragma unroll
            for (int mi = 0; mi < 2; mi++)
                #pragma unroll
                for (int n = 0; n < 4; n++) s[mi][n] = (f32x4)(0.0f);
            #pragma unroll
            for (int n = 0; n < 4; n++) {
                const short* kp = &sK[(n * 16 + l15) * KSTR + quad * 8];
                #pragma unroll
                for (int c = 0; c < 4; c++) {
                    bf16x8 kf = *(const bf16x8*)(kp + c * 32);
                    s[0][n] = __builtin_amdgcn_mfma_f32_16x16x32_bf16(qf[0][c], kf, s[0][n], 0, 0, 0);
                    s[1][n] = __builtin_amdgcn_mfma_f32_16x16x32_bf16(qf[1][c], kf, s[1][n], 0, 0, 0);
                }
            }

            #pragma unroll
            for (int mi = 0; mi < 2; mi++) {
                const int qbm = qb + mi * 16;
                const bool msk = (kv0 + 63 > qbm);
                float sv[4][4];
                #pragma unroll
                for (int n = 0; n < 4; n++)
                    #pragma unroll
                    for (int r = 0; r < 4; r++) {
                        float x = s[mi][n][r] * scale;
                        if (msk) {
                            const int kvg = kv0 + n * 16 + l15;
                            const int qg  = qbm + quad * 4 + r;
                            if (kvg > qg) x = -1e30f;
                        }
                        sv[n][r] = x;
                    }

                float alpha[4];
                #pragma unroll
                for (int r = 0; r < 4; r++) {
                    float v = fmaxf(fmaxf(sv[0][r], sv[1][r]), fmaxf(sv[2][r], sv[3][r]));
                    #pragma unroll
                    for (int m2 = 8; m2; m2 >>= 1)
                        v = fmaxf(v, __shfl_xor(v, m2, 64));
                    const float mn = fmaxf(mrow[mi][r], v);
                    alpha[r] = __expf(mrow[mi][r] - mn);
                    mrow[mi][r] = mn;
                }
                #pragma unroll
                for (int r = 0; r < 4; r++) {
                    float rs = 0.f;
                    #pragma unroll
                    for (int n = 0; n < 4; n++) {
                        const float p = __expf(sv[n][r] - mrow[mi][r]);
                        sv[n][r] = p;
                        rs += p;
                    }
                    lrow[mi][r] = lrow[mi][r] * alpha[r] + rs;
                }
                #pragma unroll
                for (int d = 0; d < 8; d++)
                    #pragma unroll
                    for (int r = 0; r < 4; r++)
                        o[mi][d][r] *= alpha[r];

                short* pb = &sP[(w * 32 + mi * 16) * PSTR];
                #pragma unroll
                for (int n = 0; n < 4; n++)
                    #pragma unroll
                    for (int r = 0; r < 4; r++)
                        pb[(quad * 4 + r) * PSTR + n * 16 + l15] = bf16bits(sv[n][r]);
            }

            #pragma unroll
            for (int c = 0; c < 2; c++) {
                bf16x8 pf0 = *(const bf16x8*)(&sP[(w * 32 + l15) * PSTR + c * 32 + quad * 8]);
                bf16x8 pf1 = *(const bf16x8*)(&sP[(w * 32 + 16 + l15) * PSTR + c * 32 + quad * 8]);
                #pragma unroll
                for (int d = 0; d < 8; d++) {
                    bf16x8 vf = *(const bf16x8*)(&sV[(d * 16 + l15) * VSTR + c * 32 + quad * 8]);
                    o[0][d] = __builtin_amdgcn_mfma_f32_16x16x32_bf16(pf0, vf, o[0][d], 0, 0, 0);
                    o[1][d] = __builtin_amdgcn_mfma_f32_16x16x32_bf16(pf1, vf, o[1][d], 0, 0, 0);
                }
            }
        }
        __syncthreads();
    }

    const int b = bh >> 4, h = bh & 15;
    #pragma unroll
    for (int mi = 0; mi < 2; mi++)
        #pragma unroll
        for (int r = 0; r < 4; r++) {
            float l = lrow[mi][r];
            #pragma unroll
            for (int m2 = 8; m2; m2 >>= 1)
                l += __shfl_xor(l, m2, 64);
            const float inv = 1.0f / l;
            const int qg = qb + mi * 16 + quad * 4 + r;
            #pragma unroll
            for (int d = 0; d < 8; d++) {
                const int col = d * 16 + l15;
                vals[(((size_t)b * S_ + qg) * H_ + h) * DH_ + col] =
                    __float2bfloat16(o[mi][d][r] * inv);
            }
        }
}

// ---------------------------------------------------------------------------
extern "C" void kernel_launch(void* const* d_in, const int* in_sizes, int n_in,
                              void* d_out, int out_size, void* d_ws, size_t ws_size,
                              hipStream_t stream)
{
    const float* x    = (const float*)d_in[0];
    const float* cos_ = (const float*)d_in[1];
    const float* sin_ = (const float*)d_in[2];
    const float* Wq   = (const float*)d_in[3];
    const float* Wk   = (const float*)d_in[4];
    const float* Wv   = (const float*)d_in[5];
    const float* Wo   = (const float*)d_in[6];
    float* out = (float*)d_out;

    const size_t NELEM = (size_t)B_ * S_ * D_;       // 8388608
    const size_t WELEM = (size_t)D_ * D_;            // 4194304

    // d_out scratch during QKV phase: 3 bf16 weights (25.2 MB <= 33.5 MB)
    __hip_bfloat16* wqb = (__hip_bfloat16*)d_out;
    __hip_bfloat16* wkb = wqb + WELEM;
    __hip_bfloat16* wvb = wkb + WELEM;
    // ws (67 MB): q,k,vt,vals. xb shares the vals region (dead before attn
    // writes vals); Wo-bf16 reuses q region (dead after attn).
    __hip_bfloat16* q    = (__hip_bfloat16*)d_ws;
    __hip_bfloat16* k    = q + NELEM;
    __hip_bfloat16* vt   = k + NELEM;
    __hip_bfloat16* vals = vt + NELEM;
    __hip_bfloat16* xb   = vals;
    __hip_bfloat16* wob  = q;

    const int M = B_ * S_, N = D_, K = D_;
    const int xcb = (int)(NELEM / (256 * 8));        // 4096 blocks
    const int wcb = (int)(WELEM / (256 * 8));        // 2048 blocks

    f2b_kernel<<<xcb, 256, 0, stream>>>(x, xb);
    f2b3_kernel<<<3 * wcb, 256, 0, stream>>>(Wq, Wk, Wv, wqb, wkb, wvb, wcb);

    gemm_qkv<<<dim3(3 * N / 128, M / 128), 256, 0, stream>>>(xb, wqb, wkb, wvb, q, k, vt);

    const int rope_blocks = B_ * H_ * S_ * 64 / 256;  // per tensor
    rope2_kernel<<<2 * rope_blocks, 256, 0, stream>>>(q, k, cos_, sin_, rope_blocks);

    attn_mfma<<<dim3(S_ / 128, B_ * H_), 256, 0, stream>>>(q, k, vt, vals);

    f2b_kernel<<<wcb, 256, 0, stream>>>(Wo, wob);
    gemm_mfma<<<dim3(N / 128, M / 128), 256, 0, stream>>>(vals, wob, out, M, N, K);
}